// Round 14
// baseline (350.835 us; speedup 1.0000x reference)
//
#include <hip/hip_runtime.h>

#define B_  16
#define CIN 512
#define C_  64
#define H_  64
#define W_  160
#define HW  (H_*W_)   // 10240

typedef __attribute__((ext_vector_type(8))) short bf16x8;
typedef __attribute__((ext_vector_type(4))) float f32x4;
typedef __attribute__((ext_vector_type(8))) unsigned short u16x8;
typedef __attribute__((ext_vector_type(4))) unsigned short u16x4;

// RNE float -> bf16
__device__ inline unsigned short f2bf(float x) {
    unsigned u = __float_as_uint(x);
    return (unsigned short)((u + 0x7FFF + ((u >> 16) & 1)) >> 16);
}
__device__ inline float bf2f(unsigned short v) {
    return __uint_as_float((unsigned)v << 16);
}

// RNE float -> bf16 hi, then RNE bf16 of the remainder (weight prep)
__device__ inline void bf16_split(float x, unsigned short& h, unsigned short& l) {
    h = f2bf(x);
    float lo = x - bf2f(h);
    l = f2bf(lo);
}

// Truncation split (gemm1 hot path)
__device__ inline void bf16_tsplit(float x, short& h, short& l) {
    unsigned u = __float_as_uint(x);
    h = (short)(u >> 16);
    float hf = __uint_as_float(u & 0xFFFF0000u);
    float lo = x - hf;
    l = (short)(__float_as_uint(lo) >> 16);
}

// ---------------- K1: pack hm_w into MFMA-fragment-ordered hi/lo bf16 ---------
// o = t*16 + (lane&15), k = ks*32 + (lane>>4)*8 + j   (A-operand layout)
__global__ __launch_bounds__(256) void k_prep_w(const float* __restrict__ hmw,
                                                unsigned short* __restrict__ wfrag) {
    int tid  = blockIdx.x * 256 + threadIdx.x;        // 0 .. 65535
    int j    = tid & 7;
    int lane = (tid >> 3) & 63;
    int t    = (tid >> 9) & 3;
    int p    = (tid >> 11) & 1;
    int ks   = tid >> 12;
    int o = t * 16 + (lane & 15);
    int k = ks * 32 + ((lane >> 4) << 3) + j;
    float val = hmw[o * CIN + k];
    unsigned short h, l;
    bf16_split(val, h, l);
    wfrag[tid] = p ? l : h;
}

// ---------------- K2: unnorm = fcn x W via bf16 hi/lo MFMA --------------------
// 256-px blocks (512 threads / 8 waves), 1 KB global_load_lds segments,
// double-buffered, 1 barrier per K-step. (Measured R12: ~95 us.)
__global__ __launch_bounds__(512, 4) void k_gemm1_mfma(const float* __restrict__ fcn,
                                                       const unsigned short* __restrict__ wfrag,
                                                       float* __restrict__ out) {
    const int lane  = threadIdx.x & 63;
    const int wv    = threadIdx.x >> 6;               // 0..7
    const int b     = blockIdx.y;
    const int pxblk = blockIdx.x * 256;               // block's 256-px window

    __shared__ float xs[2][32 * 256];                 // 2 x 32 KB

    const int chl  = (lane >> 4) << 3;
    const int pxw  = wv * 32;
    const int px16 = lane & 15;
    const unsigned short* __restrict__ wp = wfrag + lane * 8;

    const size_t gbase = (size_t)b * CIN * HW + pxblk + (lane << 2);
    const int    grow0 = wv << 2;
    const int    lbase = grow0 * 256;

#define STAGE(buf, ks)                                                                  \
    {                                                                                   \
        _Pragma("unroll")                                                               \
        for (int i = 0; i < 4; ++i) {                                                   \
            const float* g = fcn + gbase + (size_t)((ks) * 32 + grow0 + i) * HW;        \
            float* l = &xs[(buf)][lbase + i * 256];                                     \
            __builtin_amdgcn_global_load_lds(                                           \
                (const __attribute__((address_space(1))) void*)g,                       \
                (__attribute__((address_space(3))) void*)l, 16, 0, 0);                  \
        }                                                                               \
    }

    f32x4 acc[2][4];
#pragma unroll
    for (int xt = 0; xt < 2; ++xt)
#pragma unroll
        for (int t = 0; t < 4; ++t) acc[xt][t] = (f32x4)0.f;

    STAGE(0, 0);
    __syncthreads();

    int cur = 0;
#pragma unroll 1
    for (int ks = 0; ks < 16; ++ks) {
        if (ks < 15) STAGE(cur ^ 1, ks + 1);

        float xa[8], xb[8];
#pragma unroll
        for (int j = 0; j < 8; ++j) {
            const float* r = &xs[cur][(chl + j) * 256 + pxw + px16];
            xa[j] = r[0];
            xb[j] = r[16];
        }
        bf16x8 xah, xal, xbh, xbl;
#pragma unroll
        for (int j = 0; j < 8; ++j) {
            short h, l;
            bf16_tsplit(xa[j], h, l);
            xah[j] = h; xal[j] = l;
            bf16_tsplit(xb[j], h, l);
            xbh[j] = h; xbl[j] = l;
        }
        const unsigned short* __restrict__ wk = wp + (size_t)ks * 4096;
        bf16x8 wh = *reinterpret_cast<const bf16x8*>(wk);
        bf16x8 wl = *reinterpret_cast<const bf16x8*>(wk + 4 * 512);
#pragma unroll
        for (int t = 0; t < 4; ++t) {
            bf16x8 whn, wln;
            if (t < 3) {
                whn = *reinterpret_cast<const bf16x8*>(wk + (t + 1) * 512);
                wln = *reinterpret_cast<const bf16x8*>(wk + (4 + t + 1) * 512);
            }
            acc[0][t] = __builtin_amdgcn_mfma_f32_16x16x32_bf16(wh, xah, acc[0][t], 0, 0, 0);
            acc[0][t] = __builtin_amdgcn_mfma_f32_16x16x32_bf16(wh, xal, acc[0][t], 0, 0, 0);
            acc[0][t] = __builtin_amdgcn_mfma_f32_16x16x32_bf16(wl, xah, acc[0][t], 0, 0, 0);
            acc[1][t] = __builtin_amdgcn_mfma_f32_16x16x32_bf16(wh, xbh, acc[1][t], 0, 0, 0);
            acc[1][t] = __builtin_amdgcn_mfma_f32_16x16x32_bf16(wh, xbl, acc[1][t], 0, 0, 0);
            acc[1][t] = __builtin_amdgcn_mfma_f32_16x16x32_bf16(wl, xbh, acc[1][t], 0, 0, 0);
            wh = whn; wl = wln;
        }

        __syncthreads();
        cur ^= 1;
    }
#undef STAGE

    const int orow = (lane >> 4) << 2;
    float* __restrict__ op = out + (size_t)b * C_ * HW + pxblk + pxw + px16;
#pragma unroll
    for (int xt = 0; xt < 2; ++xt)
#pragma unroll
        for (int t = 0; t < 4; ++t)
#pragma unroll
            for (int reg = 0; reg < 4; ++reg)
                op[(size_t)(t * 16 + orow + reg) * HW + xt * 16] = acc[xt][t][reg];
}

// ------- K3: softmax + dsnt + FUSED depthwise conv; A written as bf16 ---------
__global__ __launch_bounds__(256) void k_softmax_dsnt_conv(const float* __restrict__ in0,
                                                           const float* __restrict__ dw,
                                                           unsigned short* __restrict__ aout,
                                                           float* __restrict__ coords) {
    const int row = blockIdx.x;                  // b*64 + c
    const int c   = row & (C_ - 1);
    const int tid = threadIdx.x;
    const float4* in04 = reinterpret_cast<const float4*>(in0 + (size_t)row * HW);
    __shared__ float rowbuf[HW];                 // 40 KB (unnorm -> exp)
    __shared__ float red[16];
    float4* r4 = reinterpret_cast<float4*>(rowbuf);

    float m = -3.402823466e38f;
    for (int j = tid; j < HW/4; j += 256) {
        float4 u = in04[j];
        r4[j] = u;
        m = fmaxf(m, fmaxf(fmaxf(u.x, u.y), fmaxf(u.z, u.w)));
    }
#pragma unroll
    for (int off = 32; off > 0; off >>= 1) m = fmaxf(m, __shfl_xor(m, off));
    if ((tid & 63) == 0) red[tid >> 6] = m;
    __syncthreads();
    m = fmaxf(fmaxf(red[0], red[1]), fmaxf(red[2], red[3]));

    const float invw = 1.f / W_, invh = 1.f / H_;
    float s = 0.f, sx = 0.f, sy = 0.f;
    for (int j = tid; j < HW/4; j += 256) {
        float4 u = r4[j];
        int e0 = j * 4;
        int h  = e0 / W_;
        int w0 = e0 - h * W_;
        float y  = (2*h + 1) * invh - 1.f;
        float x0 = (2*w0 + 1) * invw - 1.f;
        float4 e;
        e.x = __expf(u.x - m); s += e.x; sy = fmaf(e.x, y, sy); sx = fmaf(e.x, x0,          sx);
        e.y = __expf(u.y - m); s += e.y; sy = fmaf(e.y, y, sy); sx = fmaf(e.y, x0 + 2*invw, sx);
        e.z = __expf(u.z - m); s += e.z; sy = fmaf(e.z, y, sy); sx = fmaf(e.z, x0 + 4*invw, sx);
        e.w = __expf(u.w - m); s += e.w; sy = fmaf(e.w, y, sy); sx = fmaf(e.w, x0 + 6*invw, sx);
        r4[j] = e;                               // store unnormalized exp
    }
#pragma unroll
    for (int off = 32; off > 0; off >>= 1) {
        s  += __shfl_xor(s,  off);
        sx += __shfl_xor(sx, off);
        sy += __shfl_xor(sy, off);
    }
    if ((tid & 63) == 0) { int w = tid >> 6; red[4+w] = s; red[8+w] = sx; red[12+w] = sy; }
    __syncthreads();                             // also fences all r4 writes
    s  = red[4] + red[5] + red[6]  + red[7];
    sx = red[8] + red[9] + red[10] + red[11];
    sy = red[12] + red[13] + red[14] + red[15];
    float inv = 1.f / s;

    if (tid == 0) {
        coords[row*2 + 0] = sx * inv;
        coords[row*2 + 1] = sy * inv;
    }

    float wv[25];
#pragma unroll
    for (int k = 0; k < 25; ++k) wv[k] = dw[c * 25 + k];

    u16x4* aout4 = reinterpret_cast<u16x4*>(aout + (size_t)row * HW);
    for (int j = tid; j < HW/4; j += 256) {
        int h  = j / (W_/4);
        int w4 = j - h * (W_/4);
        int w4m = (w4 > 0) ? w4 - 1 : 0;
        int w4p = (w4 < W_/4 - 1) ? w4 + 1 : W_/4 - 1;
        float a0 = 0.f, a1 = 0.f, a2 = 0.f, a3 = 0.f;
#pragma unroll
        for (int dy = 0; dy < 5; ++dy) {
            int rr = h + dy - 2;
            bool rok = (rr >= 0) && (rr < H_);
            int rc = rok ? rr : 0;
            const float4* rp = reinterpret_cast<const float4*>(rowbuf + rc * W_);
            float4 L = rp[w4m];
            float4 M = rp[w4];
            float4 R = rp[w4p];
            float f[12];
            f[0]=L.x; f[1]=L.y; f[2]=L.z; f[3]=L.w;
            f[4]=M.x; f[5]=M.y; f[6]=M.z; f[7]=M.w;
            f[8]=R.x; f[9]=R.y; f[10]=R.z; f[11]=R.w;
            if (!rok) {
#pragma unroll
                for (int q = 0; q < 12; ++q) f[q] = 0.f;
            }
            if (w4 == 0)          { f[0]=f[1]=f[2]=f[3] = 0.f; }
            if (w4 == W_/4 - 1)   { f[8]=f[9]=f[10]=f[11] = 0.f; }
            const float* wr = wv + dy * 5;
#pragma unroll
            for (int dx = 0; dx < 5; ++dx) {
                float wt = wr[dx];
                a0 = fmaf(f[2 + 0 + dx], wt, a0);
                a1 = fmaf(f[2 + 1 + dx], wt, a1);
                a2 = fmaf(f[2 + 2 + dx], wt, a2);
                a3 = fmaf(f[2 + 3 + dx], wt, a3);
            }
        }
        u16x4 ov;
        ov[0] = f2bf(a0 * inv); ov[1] = f2bf(a1 * inv);
        ov[2] = f2bf(a2 * inv); ov[3] = f2bf(a3 * inv);
        aout4[j] = ov;
    }
}

// ------- K5: FULL relation pipeline in one kernel (per-batch block) -----------
// 1024 threads = 16 waves: wave w -> (cg = w&3 c-row group, kc = w>>2 K-chunk).
// Register-accumulated A·A^T over K-chunk (same-fragment trick, verified R13),
// cross-wave reduce via LDS planes, rowmin-softmax, pack R as MFMA hi/lo frags.
__global__ __launch_bounds__(1024) void k_relation(const unsigned short* __restrict__ A,
                                                   unsigned short* __restrict__ rfrag) {
    const int b    = blockIdx.x;
    const int tid  = threadIdx.x;
    const int lane = tid & 63;
    const int w    = tid >> 6;                  // 0..15
    const int cg   = w & 3;                     // c-row group
    const int kc   = w >> 2;                    // K-chunk (0..3), 2560 hw each
    const unsigned short* __restrict__ ab = A + (size_t)b * C_ * HW;
    const int r16 = lane & 15, h8 = (lane >> 4) << 3;
    const unsigned short* __restrict__ own = ab + (size_t)(cg * 16 + r16) * HW;

    __shared__ float rel4[4][64][64];           // 64 KB partial planes
    __shared__ float Rs[64][64];                // 16 KB

    f32x4 acc[4];
#pragma unroll
    for (int d = 0; d < 4; ++d) acc[d] = (f32x4)0.f;

#pragma unroll 1
    for (int kk = 0; kk < 80; ++kk) {
        const int hw0 = kc * 2560 + kk * 32 + h8;
        bf16x8 fra = *reinterpret_cast<const bf16x8*>(own + hw0);
#pragma unroll
        for (int d = 0; d < 4; ++d) {
            bf16x8 frb = *reinterpret_cast<const bf16x8*>(ab + (size_t)(d * 16 + r16) * HW + hw0);
            acc[d] = __builtin_amdgcn_mfma_f32_16x16x32_bf16(fra, frb, acc[d], 0, 0, 0);
        }
    }

    const int crow = cg * 16 + ((lane >> 4) << 2);
#pragma unroll
    for (int d = 0; d < 4; ++d)
#pragma unroll
        for (int reg = 0; reg < 4; ++reg)
            rel4[kc][crow + reg][d * 16 + r16] = acc[d][reg];
    __syncthreads();

    // reduce planes + rowmin softmax (rows 0..63 by tid<64)
    if (tid < 64) {
        int cc = tid;
        float rowv[64];
        float mn = 3.402823466e38f;
#pragma unroll 4
        for (int d = 0; d < 64; ++d) {
            float s = rel4[0][cc][d] + rel4[1][cc][d] + rel4[2][cc][d] + rel4[3][cc][d];
            rowv[d] = s;
            mn = fminf(mn, s);
        }
        float s = 0.f;
#pragma unroll 4
        for (int d = 0; d < 64; ++d) s += __expf(mn - rowv[d]);
        float inv = 1.f / s;
#pragma unroll 4
        for (int d = 0; d < 64; ++d)
            Rs[cc][d] = __expf(mn - rowv[d]) * inv;
    }
    __syncthreads();

    // pack R as MFMA-fragment-ordered hi/lo bf16 (1024 entries, one per thread)
    {
        int idx  = tid;
        int rest = idx >> 6;          // ks*8 + p*4 + t
        int t  = rest & 3;
        int p  = (rest >> 2) & 1;
        int ks = rest >> 3;
        int o  = t * 16 + (lane & 15);
        int d0 = ks * 32 + ((lane >> 4) << 3);
        bf16x8 v;
#pragma unroll
        for (int j = 0; j < 8; ++j) {
            unsigned short h, l;
            bf16_split(Rs[o][d0 + j], h, l);
            v[j] = (short)(p ? l : h);
        }
        *reinterpret_cast<bf16x8*>(rfrag + (size_t)b * 8192 + idx * 8) = v;
    }
}

// ------- K7: feat_e = R·A (A single bf16, R hi/lo); t=(fe+A)*fu -> bf16 -------
__global__ __launch_bounds__(256, 4) void k_feate_mfma(const unsigned short* __restrict__ A,
                                                       const unsigned short* __restrict__ rfrag,
                                                       const float* __restrict__ fu,
                                                       unsigned short* __restrict__ tout) {
    const int lane = threadIdx.x & 63;
    const int wv   = threadIdx.x >> 6;
    const int b    = blockIdx.y;
    const int px0  = blockIdx.x * 128 + wv * 32;

    const int pxa = px0 + (lane & 15);
    const int chl = (lane >> 4) << 3;
    const unsigned short* __restrict__ apx = A + ((size_t)b * C_ + chl) * HW + pxa;
    const unsigned short* __restrict__ rp = rfrag + (size_t)b * 8192 + lane * 8;

    f32x4 acc[2][4];
#pragma unroll
    for (int xt = 0; xt < 2; ++xt)
#pragma unroll
        for (int t = 0; t < 4; ++t) acc[xt][t] = (f32x4)0.f;

#pragma unroll 1
    for (int ks = 0; ks < 2; ++ks) {
        bf16x8 xa, xb;
#pragma unroll
        for (int j = 0; j < 8; ++j) {
            const unsigned short* p0 = apx + (size_t)(ks * 32 + j) * HW;
            xa[j] = (short)p0[0];
            xb[j] = (short)p0[16];
        }
        const unsigned short* __restrict__ rk = rp + (size_t)ks * 8 * 512;
        bf16x8 rh = *reinterpret_cast<const bf16x8*>(rk);
        bf16x8 rl = *reinterpret_cast<const bf16x8*>(rk + 4 * 512);
#pragma unroll
        for (int t = 0; t < 4; ++t) {
            bf16x8 rhn, rln;
            if (t < 3) {
                rhn = *reinterpret_cast<const bf16x8*>(rk + (t + 1) * 512);
                rln = *reinterpret_cast<const bf16x8*>(rk + (4 + t + 1) * 512);
            }
            acc[0][t] = __builtin_amdgcn_mfma_f32_16x16x32_bf16(rh, xa, acc[0][t], 0, 0, 0);
            acc[0][t] = __builtin_amdgcn_mfma_f32_16x16x32_bf16(rl, xa, acc[0][t], 0, 0, 0);
            acc[1][t] = __builtin_amdgcn_mfma_f32_16x16x32_bf16(rh, xb, acc[1][t], 0, 0, 0);
            acc[1][t] = __builtin_amdgcn_mfma_f32_16x16x32_bf16(rl, xb, acc[1][t], 0, 0, 0);
            rh = rhn; rl = rln;
        }
    }

    // epilogue: t = (feat_e + A) * fu, write bf16
    const int orow = (lane >> 4) << 2;
    const unsigned short* __restrict__ ares = A + (size_t)b * C_ * HW + px0 + (lane & 15);
    unsigned short* __restrict__ op        = tout + (size_t)b * C_ * HW + px0 + (lane & 15);
#pragma unroll
    for (int xt = 0; xt < 2; ++xt)
#pragma unroll
        for (int t = 0; t < 4; ++t)
#pragma unroll
            for (int reg = 0; reg < 4; ++reg) {
                const int oc = t * 16 + orow + reg;
                float r = acc[xt][t][reg] + bf2f(ares[(size_t)oc * HW + xt * 16]);
                op[(size_t)oc * HW + xt * 16] = f2bf(r * fu[oc]);
            }
}

// ---------------- K8: row softmax (bf16 input) + dsnt; fp32 heatmap out -------
__global__ __launch_bounds__(256) void k_softmax_dsnt(const unsigned short* __restrict__ in0,
                                                      float* __restrict__ pout,
                                                      float* __restrict__ coords) {
    const int row = blockIdx.x;                  // b*64 + c
    const int tid = threadIdx.x;
    const u16x8* in08 = reinterpret_cast<const u16x8*>(in0 + (size_t)row * HW);
    float4*      out4 = reinterpret_cast<float4*>(pout + (size_t)row * HW);
    __shared__ float rowbuf[HW];                 // 40 KB
    __shared__ float red[16];
    float4* r4 = reinterpret_cast<float4*>(rowbuf);

    float m = -3.402823466e38f;
    for (int j = tid; j < HW/8; j += 256) {
        u16x8 u = in08[j];
        float4 a, bv;
        a.x  = bf2f(u[0]); a.y  = bf2f(u[1]); a.z  = bf2f(u[2]); a.w  = bf2f(u[3]);
        bv.x = bf2f(u[4]); bv.y = bf2f(u[5]); bv.z = bf2f(u[6]); bv.w = bf2f(u[7]);
        r4[2*j]     = a;
        r4[2*j + 1] = bv;
        m = fmaxf(m, fmaxf(fmaxf(a.x, a.y), fmaxf(a.z, a.w)));
        m = fmaxf(m, fmaxf(fmaxf(bv.x, bv.y), fmaxf(bv.z, bv.w)));
    }
#pragma unroll
    for (int off = 32; off > 0; off >>= 1) m = fmaxf(m, __shfl_xor(m, off));
    if ((tid & 63) == 0) red[tid >> 6] = m;
    __syncthreads();
    m = fmaxf(fmaxf(red[0], red[1]), fmaxf(red[2], red[3]));

    const float invw = 1.f / W_, invh = 1.f / H_;
    float s = 0.f, sx = 0.f, sy = 0.f;
    for (int j = tid; j < HW/4; j += 256) {
        float4 u = r4[j];
        int e0 = j * 4;
        int h  = e0 / W_;
        int w0 = e0 - h * W_;
        float y  = (2*h + 1) * invh - 1.f;
        float x0 = (2*w0 + 1) * invw - 1.f;
        float4 e;
        e.x = __expf(u.x - m); s += e.x; sy = fmaf(e.x, y, sy); sx = fmaf(e.x, x0,          sx);
        e.y = __expf(u.y - m); s += e.y; sy = fmaf(e.y, y, sy); sx = fmaf(e.y, x0 + 2*invw, sx);
        e.z = __expf(u.z - m); s += e.z; sy = fmaf(e.z, y, sy); sx = fmaf(e.z, x0 + 4*invw, sx);
        e.w = __expf(u.w - m); s += e.w; sy = fmaf(e.w, y, sy); sx = fmaf(e.w, x0 + 6*invw, sx);
        r4[j] = e;                               // store unnormalized exp
    }
#pragma unroll
    for (int off = 32; off > 0; off >>= 1) {
        s  += __shfl_xor(s,  off);
        sx += __shfl_xor(sx, off);
        sy += __shfl_xor(sy, off);
    }
    if ((tid & 63) == 0) { int w = tid >> 6; red[4+w] = s; red[8+w] = sx; red[12+w] = sy; }
    __syncthreads();
    s  = red[4] + red[5] + red[6]  + red[7];
    sx = red[8] + red[9] + red[10] + red[11];
    sy = red[12] + red[13] + red[14] + red[15];
    float inv = 1.f / s;

    for (int j = tid; j < HW/4; j += 256) {
        float4 e = r4[j];
        e.x *= inv; e.y *= inv; e.z *= inv; e.w *= inv;
        out4[j] = e;
    }
    if (tid == 0) {
        coords[row*2 + 0] = sx * inv;
        coords[row*2 + 1] = sy * inv;
    }
}

// ------------------------------------------------------------------------------
extern "C" void kernel_launch(void* const* d_in, const int* in_sizes, int n_in,
                              void* d_out, int out_size, void* d_ws, size_t ws_size,
                              hipStream_t stream) {
    const float* fcn = (const float*)d_in[0];
    const float* hmw = (const float*)d_in[1];
    const float* dww = (const float*)d_in[2];
    const float* fuw = (const float*)d_in[3];
    float* out = (float*)d_out;
    char* ws = (char*)d_ws;

    size_t off = 0;
    unsigned short* wfrag = (unsigned short*)(ws + off); off += 131072;          // 128 KB
    float*          buf1  = (float*)         (ws + off); off += 41943040;        // 42 MB (unnorm)
    unsigned short* abf   = (unsigned short*)(ws + off); off += 20971520;        // 21 MB (A bf16)
    unsigned short* rfrag = (unsigned short*)(ws + off); off += 262144;          // 256 KB
    unsigned short* tbuf  = (unsigned short*)(ws + off); off += 20971520;        // 21 MB (t bf16)

    float* hm2            = out + 4096;   // final heatmaps (fp32)
    float* final_coords   = out;
    float* interme_coords = out + 2048;

    hipLaunchKernelGGL(k_prep_w,            dim3(256),      dim3(256),  0, stream, hmw, wfrag);
    hipLaunchKernelGGL(k_gemm1_mfma,        dim3(40, 16),   dim3(512),  0, stream, fcn, wfrag, buf1);
    hipLaunchKernelGGL(k_softmax_dsnt_conv, dim3(1024),     dim3(256),  0, stream, buf1, dww, abf, interme_coords);
    hipLaunchKernelGGL(k_relation,          dim3(16),       dim3(1024), 0, stream, abf, rfrag);
    hipLaunchKernelGGL(k_feate_mfma,        dim3(80, 16),   dim3(256),  0, stream, abf, rfrag, fuw, tbuf);
    hipLaunchKernelGGL(k_softmax_dsnt,      dim3(1024),     dim3(256),  0, stream, tbuf, hm2, final_coords);
}

// Round 15
// 194.830 us; speedup vs baseline: 1.8007x; 1.8007x over previous
//
#include <hip/hip_runtime.h>

#define B_  16
#define CIN 512
#define C_  64
#define H_  64
#define W_  160
#define HW  (H_*W_)   // 10240
#define NCH 16        // relation hw-chunks per batch (640 hw each)

typedef __attribute__((ext_vector_type(8))) short bf16x8;
typedef __attribute__((ext_vector_type(4))) float f32x4;
typedef __attribute__((ext_vector_type(8))) unsigned short u16x8;
typedef __attribute__((ext_vector_type(4))) unsigned short u16x4;

// RNE float -> bf16
__device__ inline unsigned short f2bf(float x) {
    unsigned u = __float_as_uint(x);
    return (unsigned short)((u + 0x7FFF + ((u >> 16) & 1)) >> 16);
}
__device__ inline float bf2f(unsigned short v) {
    return __uint_as_float((unsigned)v << 16);
}

// RNE float -> bf16 hi, then RNE bf16 of the remainder (weight prep)
__device__ inline void bf16_split(float x, unsigned short& h, unsigned short& l) {
    h = f2bf(x);
    float lo = x - bf2f(h);
    l = f2bf(lo);
}

// Truncation split (gemm1 hot path)
__device__ inline void bf16_tsplit(float x, short& h, short& l) {
    unsigned u = __float_as_uint(x);
    h = (short)(u >> 16);
    float hf = __uint_as_float(u & 0xFFFF0000u);
    float lo = x - hf;
    l = (short)(__float_as_uint(lo) >> 16);
}

// ---------------- K1: pack hm_w into MFMA-fragment-ordered hi/lo bf16 ---------
// o = t*16 + (lane&15), k = ks*32 + (lane>>4)*8 + j   (A-operand layout)
__global__ __launch_bounds__(256) void k_prep_w(const float* __restrict__ hmw,
                                                unsigned short* __restrict__ wfrag) {
    int tid  = blockIdx.x * 256 + threadIdx.x;        // 0 .. 65535
    int j    = tid & 7;
    int lane = (tid >> 3) & 63;
    int t    = (tid >> 9) & 3;
    int p    = (tid >> 11) & 1;
    int ks   = tid >> 12;
    int o = t * 16 + (lane & 15);
    int k = ks * 32 + ((lane >> 4) << 3) + j;
    float val = hmw[o * CIN + k];
    unsigned short h, l;
    bf16_split(val, h, l);
    wfrag[tid] = p ? l : h;
}

// ---------------- K2: unnorm = fcn x W via bf16 hi/lo MFMA --------------------
// 256-px blocks (512 threads / 8 waves), 1 KB global_load_lds segments,
// double-buffered, 1 barrier per K-step. NEW: C-tile staged through LDS so
// global writes are per-wave 1 KB contiguous segments (was 4x64 B / store).
__global__ __launch_bounds__(512, 4) void k_gemm1_mfma(const float* __restrict__ fcn,
                                                       const unsigned short* __restrict__ wfrag,
                                                       float* __restrict__ out) {
    const int lane  = threadIdx.x & 63;
    const int wv    = threadIdx.x >> 6;               // 0..7
    const int b     = blockIdx.y;
    const int pxblk = blockIdx.x * 256;               // block's 256-px window

    __shared__ float xs[2][32 * 256];                 // 2 x 32 KB (also C-stage)

    const int chl  = (lane >> 4) << 3;
    const int pxw  = wv * 32;
    const int px16 = lane & 15;
    const unsigned short* __restrict__ wp = wfrag + lane * 8;

    const size_t gbase = (size_t)b * CIN * HW + pxblk + (lane << 2);
    const int    grow0 = wv << 2;
    const int    lbase = grow0 * 256;

#define STAGE(buf, ks)                                                                  \
    {                                                                                   \
        _Pragma("unroll")                                                               \
        for (int i = 0; i < 4; ++i) {                                                   \
            const float* g = fcn + gbase + (size_t)((ks) * 32 + grow0 + i) * HW;        \
            float* l = &xs[(buf)][lbase + i * 256];                                     \
            __builtin_amdgcn_global_load_lds(                                           \
                (const __attribute__((address_space(1))) void*)g,                       \
                (__attribute__((address_space(3))) void*)l, 16, 0, 0);                  \
        }                                                                               \
    }

    f32x4 acc[2][4];
#pragma unroll
    for (int xt = 0; xt < 2; ++xt)
#pragma unroll
        for (int t = 0; t < 4; ++t) acc[xt][t] = (f32x4)0.f;

    STAGE(0, 0);
    __syncthreads();

    int cur = 0;
#pragma unroll 1
    for (int ks = 0; ks < 16; ++ks) {
        if (ks < 15) STAGE(cur ^ 1, ks + 1);

        float xa[8], xb[8];
#pragma unroll
        for (int j = 0; j < 8; ++j) {
            const float* r = &xs[cur][(chl + j) * 256 + pxw + px16];
            xa[j] = r[0];
            xb[j] = r[16];
        }
        bf16x8 xah, xal, xbh, xbl;
#pragma unroll
        for (int j = 0; j < 8; ++j) {
            short h, l;
            bf16_tsplit(xa[j], h, l);
            xah[j] = h; xal[j] = l;
            bf16_tsplit(xb[j], h, l);
            xbh[j] = h; xbl[j] = l;
        }
        const unsigned short* __restrict__ wk = wp + (size_t)ks * 4096;
        bf16x8 wh = *reinterpret_cast<const bf16x8*>(wk);
        bf16x8 wl = *reinterpret_cast<const bf16x8*>(wk + 4 * 512);
#pragma unroll
        for (int t = 0; t < 4; ++t) {
            bf16x8 whn, wln;
            if (t < 3) {
                whn = *reinterpret_cast<const bf16x8*>(wk + (t + 1) * 512);
                wln = *reinterpret_cast<const bf16x8*>(wk + (4 + t + 1) * 512);
            }
            acc[0][t] = __builtin_amdgcn_mfma_f32_16x16x32_bf16(wh, xah, acc[0][t], 0, 0, 0);
            acc[0][t] = __builtin_amdgcn_mfma_f32_16x16x32_bf16(wh, xal, acc[0][t], 0, 0, 0);
            acc[0][t] = __builtin_amdgcn_mfma_f32_16x16x32_bf16(wl, xah, acc[0][t], 0, 0, 0);
            acc[1][t] = __builtin_amdgcn_mfma_f32_16x16x32_bf16(wh, xbh, acc[1][t], 0, 0, 0);
            acc[1][t] = __builtin_amdgcn_mfma_f32_16x16x32_bf16(wh, xbl, acc[1][t], 0, 0, 0);
            acc[1][t] = __builtin_amdgcn_mfma_f32_16x16x32_bf16(wl, xbh, acc[1][t], 0, 0, 0);
            wh = whn; wl = wln;
        }

        __syncthreads();
        cur ^= 1;
    }
#undef STAGE

    // ---- epilogue: stage C-tile (64ch x 256px) in LDS, write 1 KB rows ----
    float* cst = &xs[0][0];                           // 64 KB, free after loop
    const int orow = (lane >> 4) << 2;
#pragma unroll
    for (int xt = 0; xt < 2; ++xt)
#pragma unroll
        for (int t = 0; t < 4; ++t)
#pragma unroll
            for (int reg = 0; reg < 4; ++reg)
                cst[(t * 16 + orow + reg) * 256 + pxw + px16 + xt * 16] = acc[xt][t][reg];
    __syncthreads();
    float* __restrict__ ob = out + (size_t)b * C_ * HW + pxblk;
    const float4* cst4 = reinterpret_cast<const float4*>(cst);
#pragma unroll
    for (int k = 0; k < 8; ++k) {
        int flat4 = (int)threadIdx.x + k * 512;       // 0..4095
        int ch  = flat4 >> 6;
        int px4 = flat4 & 63;
        *reinterpret_cast<float4*>(ob + (size_t)ch * HW + px4 * 4) = cst4[flat4];
    }
}

// ------- K3: softmax + dsnt + FUSED depthwise conv; A written as bf16 ---------
__global__ __launch_bounds__(256) void k_softmax_dsnt_conv(const float* __restrict__ in0,
                                                           const float* __restrict__ dw,
                                                           unsigned short* __restrict__ aout,
                                                           float* __restrict__ coords) {
    const int row = blockIdx.x;                  // b*64 + c
    const int c   = row & (C_ - 1);
    const int tid = threadIdx.x;
    const float4* in04 = reinterpret_cast<const float4*>(in0 + (size_t)row * HW);
    __shared__ float rowbuf[HW];                 // 40 KB (unnorm -> exp)
    __shared__ float red[16];
    float4* r4 = reinterpret_cast<float4*>(rowbuf);

    float m = -3.402823466e38f;
    for (int j = tid; j < HW/4; j += 256) {
        float4 u = in04[j];
        r4[j] = u;
        m = fmaxf(m, fmaxf(fmaxf(u.x, u.y), fmaxf(u.z, u.w)));
    }
#pragma unroll
    for (int off = 32; off > 0; off >>= 1) m = fmaxf(m, __shfl_xor(m, off));
    if ((tid & 63) == 0) red[tid >> 6] = m;
    __syncthreads();
    m = fmaxf(fmaxf(red[0], red[1]), fmaxf(red[2], red[3]));

    const float invw = 1.f / W_, invh = 1.f / H_;
    float s = 0.f, sx = 0.f, sy = 0.f;
    for (int j = tid; j < HW/4; j += 256) {
        float4 u = r4[j];
        int e0 = j * 4;
        int h  = e0 / W_;
        int w0 = e0 - h * W_;
        float y  = (2*h + 1) * invh - 1.f;
        float x0 = (2*w0 + 1) * invw - 1.f;
        float4 e;
        e.x = __expf(u.x - m); s += e.x; sy = fmaf(e.x, y, sy); sx = fmaf(e.x, x0,          sx);
        e.y = __expf(u.y - m); s += e.y; sy = fmaf(e.y, y, sy); sx = fmaf(e.y, x0 + 2*invw, sx);
        e.z = __expf(u.z - m); s += e.z; sy = fmaf(e.z, y, sy); sx = fmaf(e.z, x0 + 4*invw, sx);
        e.w = __expf(u.w - m); s += e.w; sy = fmaf(e.w, y, sy); sx = fmaf(e.w, x0 + 6*invw, sx);
        r4[j] = e;                               // store unnormalized exp
    }
#pragma unroll
    for (int off = 32; off > 0; off >>= 1) {
        s  += __shfl_xor(s,  off);
        sx += __shfl_xor(sx, off);
        sy += __shfl_xor(sy, off);
    }
    if ((tid & 63) == 0) { int w = tid >> 6; red[4+w] = s; red[8+w] = sx; red[12+w] = sy; }
    __syncthreads();                             // also fences all r4 writes
    s  = red[4] + red[5] + red[6]  + red[7];
    sx = red[8] + red[9] + red[10] + red[11];
    sy = red[12] + red[13] + red[14] + red[15];
    float inv = 1.f / s;

    if (tid == 0) {
        coords[row*2 + 0] = sx * inv;
        coords[row*2 + 1] = sy * inv;
    }

    float wv[25];
#pragma unroll
    for (int k = 0; k < 25; ++k) wv[k] = dw[c * 25 + k];

    u16x4* aout4 = reinterpret_cast<u16x4*>(aout + (size_t)row * HW);
    for (int j = tid; j < HW/4; j += 256) {
        int h  = j / (W_/4);
        int w4 = j - h * (W_/4);
        int w4m = (w4 > 0) ? w4 - 1 : 0;
        int w4p = (w4 < W_/4 - 1) ? w4 + 1 : W_/4 - 1;
        float a0 = 0.f, a1 = 0.f, a2 = 0.f, a3 = 0.f;
#pragma unroll
        for (int dy = 0; dy < 5; ++dy) {
            int rr = h + dy - 2;
            bool rok = (rr >= 0) && (rr < H_);
            int rc = rok ? rr : 0;
            const float4* rp = reinterpret_cast<const float4*>(rowbuf + rc * W_);
            float4 L = rp[w4m];
            float4 M = rp[w4];
            float4 R = rp[w4p];
            float f[12];
            f[0]=L.x; f[1]=L.y; f[2]=L.z; f[3]=L.w;
            f[4]=M.x; f[5]=M.y; f[6]=M.z; f[7]=M.w;
            f[8]=R.x; f[9]=R.y; f[10]=R.z; f[11]=R.w;
            if (!rok) {
#pragma unroll
                for (int q = 0; q < 12; ++q) f[q] = 0.f;
            }
            if (w4 == 0)          { f[0]=f[1]=f[2]=f[3] = 0.f; }
            if (w4 == W_/4 - 1)   { f[8]=f[9]=f[10]=f[11] = 0.f; }
            const float* wr = wv + dy * 5;
#pragma unroll
            for (int dx = 0; dx < 5; ++dx) {
                float wt = wr[dx];
                a0 = fmaf(f[2 + 0 + dx], wt, a0);
                a1 = fmaf(f[2 + 1 + dx], wt, a1);
                a2 = fmaf(f[2 + 2 + dx], wt, a2);
                a3 = fmaf(f[2 + 3 + dx], wt, a3);
            }
        }
        u16x4 ov;
        ov[0] = f2bf(a0 * inv); ov[1] = f2bf(a1 * inv);
        ov[2] = f2bf(a2 * inv); ov[3] = f2bf(a3 * inv);
        aout4[j] = ov;
    }
}

// ------- K5: relation partials A·A^T via MFMA (no LDS, no barriers) -----------
// A-op and B-op lane maps are identical for 16x16x32, so one fragment serves
// both roles. rel is symmetric so operand-order transposition is harmless.
__global__ __launch_bounds__(256) void k_rel_partial(const unsigned short* __restrict__ A,
                                                     float* __restrict__ part) {
    const int b  = blockIdx.y, ch = blockIdx.x;
    const int lane = threadIdx.x & 63;
    const int w    = threadIdx.x >> 6;          // wave's cg (0..3)
    const int hwb  = ch * (HW / NCH);           // 640-hw chunk
    const unsigned short* __restrict__ ab = A + (size_t)b * C_ * HW;
    const int r16 = lane & 15, h8 = (lane >> 4) << 3;
    const unsigned short* __restrict__ own = ab + (size_t)(w * 16 + r16) * HW;

    f32x4 acc[4];
#pragma unroll
    for (int d = 0; d < 4; ++d) acc[d] = (f32x4)0.f;

#pragma unroll 1
    for (int kk = 0; kk < (HW / NCH) / 32; ++kk) {
        const int hw0 = hwb + kk * 32 + h8;
        bf16x8 fra = *reinterpret_cast<const bf16x8*>(own + hw0);
#pragma unroll
        for (int d = 0; d < 4; ++d) {
            bf16x8 frb = *reinterpret_cast<const bf16x8*>(ab + (size_t)(d * 16 + r16) * HW + hw0);
            acc[d] = __builtin_amdgcn_mfma_f32_16x16x32_bf16(fra, frb, acc[d], 0, 0, 0);
        }
    }

    float* __restrict__ pp = part + (size_t)(b * NCH + ch) * 4096;
    const int crow = w * 16 + ((lane >> 4) << 2);
#pragma unroll
    for (int d = 0; d < 4; ++d)
#pragma unroll
        for (int reg = 0; reg < 4; ++reg)
            pp[(crow + reg) * 64 + d * 16 + r16] = acc[d][reg];
}

// ------ K6: reduce partials, rowmax-sub softmax, pack R as MFMA frags ---------
__global__ __launch_bounds__(256) void k_rel_finalize(const float* __restrict__ part,
                                                      unsigned short* __restrict__ rfrag) {
    const int b = blockIdx.x;
    __shared__ float rel[64][65];
    __shared__ float Rs[64][64];
    for (int e = threadIdx.x; e < 4096; e += 256) {
        float s = 0.f;
        for (int k = 0; k < NCH; ++k) s += part[(size_t)(b * NCH + k) * 4096 + e];
        rel[e >> 6][e & 63] = s;
    }
    __syncthreads();
    if (threadIdx.x < 64) {
        int cc = threadIdx.x;
        // softmax(rowmax - r) == exp(rowmin - r) / sum(exp(rowmin - r))
        float mn = rel[cc][0];
        for (int d = 1; d < 64; ++d) mn = fminf(mn, rel[cc][d]);
        float s = 0.f;
        for (int d = 0; d < 64; ++d) s += __expf(mn - rel[cc][d]);
        float inv = 1.f / s;
        for (int d = 0; d < 64; ++d)
            Rs[cc][d] = __expf(mn - rel[cc][d]) * inv;
    }
    __syncthreads();
    unsigned short* __restrict__ rb = rfrag + (size_t)b * 8192;
    for (int idx = threadIdx.x; idx < 1024; idx += 256) {
        int lane = idx & 63;
        int rest = idx >> 6;          // ks*8 + p*4 + t
        int t  = rest & 3;
        int p  = (rest >> 2) & 1;
        int ks = rest >> 3;
        int o  = t * 16 + (lane & 15);
        int d0 = ks * 32 + ((lane >> 4) << 3);
        bf16x8 v;
#pragma unroll
        for (int j = 0; j < 8; ++j) {
            unsigned short h, l;
            bf16_split(Rs[o][d0 + j], h, l);
            v[j] = (short)(p ? l : h);
        }
        *reinterpret_cast<bf16x8*>(rb + idx * 8) = v;
    }
}

// ------- K7: feat_e = R·A (A single bf16, R hi/lo); t=(fe+A)*fu -> bf16 -------
__global__ __launch_bounds__(256, 4) void k_feate_mfma(const unsigned short* __restrict__ A,
                                                       const unsigned short* __restrict__ rfrag,
                                                       const float* __restrict__ fu,
                                                       unsigned short* __restrict__ tout) {
    const int lane = threadIdx.x & 63;
    const int wv   = threadIdx.x >> 6;
    const int b    = blockIdx.y;
    const int px0  = blockIdx.x * 128 + wv * 32;

    const int pxa = px0 + (lane & 15);
    const int chl = (lane >> 4) << 3;
    const unsigned short* __restrict__ apx = A + ((size_t)b * C_ + chl) * HW + pxa;
    const unsigned short* __restrict__ rp = rfrag + (size_t)b * 8192 + lane * 8;

    f32x4 acc[2][4];
#pragma unroll
    for (int xt = 0; xt < 2; ++xt)
#pragma unroll
        for (int t = 0; t < 4; ++t) acc[xt][t] = (f32x4)0.f;

#pragma unroll 1
    for (int ks = 0; ks < 2; ++ks) {
        bf16x8 xa, xb;
#pragma unroll
        for (int j = 0; j < 8; ++j) {
            const unsigned short* p0 = apx + (size_t)(ks * 32 + j) * HW;
            xa[j] = (short)p0[0];
            xb[j] = (short)p0[16];
        }
        const unsigned short* __restrict__ rk = rp + (size_t)ks * 8 * 512;
        bf16x8 rh = *reinterpret_cast<const bf16x8*>(rk);
        bf16x8 rl = *reinterpret_cast<const bf16x8*>(rk + 4 * 512);
#pragma unroll
        for (int t = 0; t < 4; ++t) {
            bf16x8 rhn, rln;
            if (t < 3) {
                rhn = *reinterpret_cast<const bf16x8*>(rk + (t + 1) * 512);
                rln = *reinterpret_cast<const bf16x8*>(rk + (4 + t + 1) * 512);
            }
            acc[0][t] = __builtin_amdgcn_mfma_f32_16x16x32_bf16(rh, xa, acc[0][t], 0, 0, 0);
            acc[0][t] = __builtin_amdgcn_mfma_f32_16x16x32_bf16(rl, xa, acc[0][t], 0, 0, 0);
            acc[1][t] = __builtin_amdgcn_mfma_f32_16x16x32_bf16(rh, xb, acc[1][t], 0, 0, 0);
            acc[1][t] = __builtin_amdgcn_mfma_f32_16x16x32_bf16(rl, xb, acc[1][t], 0, 0, 0);
            rh = rhn; rl = rln;
        }
    }

    // epilogue: t = (feat_e + A) * fu, write bf16
    const int orow = (lane >> 4) << 2;
    const unsigned short* __restrict__ ares = A + (size_t)b * C_ * HW + px0 + (lane & 15);
    unsigned short* __restrict__ op        = tout + (size_t)b * C_ * HW + px0 + (lane & 15);
#pragma unroll
    for (int xt = 0; xt < 2; ++xt)
#pragma unroll
        for (int t = 0; t < 4; ++t)
#pragma unroll
            for (int reg = 0; reg < 4; ++reg) {
                const int oc = t * 16 + orow + reg;
                float r = acc[xt][t][reg] + bf2f(ares[(size_t)oc * HW + xt * 16]);
                op[(size_t)oc * HW + xt * 16] = f2bf(r * fu[oc]);
            }
}

// ---------------- K8: row softmax (bf16 input) + dsnt; fp32 heatmap out -------
__global__ __launch_bounds__(256) void k_softmax_dsnt(const unsigned short* __restrict__ in0,
                                                      float* __restrict__ pout,
                                                      float* __restrict__ coords) {
    const int row = blockIdx.x;                  // b*64 + c
    const int tid = threadIdx.x;
    const u16x8* in08 = reinterpret_cast<const u16x8*>(in0 + (size_t)row * HW);
    float4*      out4 = reinterpret_cast<float4*>(pout + (size_t)row * HW);
    __shared__ float rowbuf[HW];                 // 40 KB
    __shared__ float red[16];
    float4* r4 = reinterpret_cast<float4*>(rowbuf);

    float m = -3.402823466e38f;
    for (int j = tid; j < HW/8; j += 256) {
        u16x8 u = in08[j];
        float4 a, bv;
        a.x  = bf2f(u[0]); a.y  = bf2f(u[1]); a.z  = bf2f(u[2]); a.w  = bf2f(u[3]);
        bv.x = bf2f(u[4]); bv.y = bf2f(u[5]); bv.z = bf2f(u[6]); bv.w = bf2f(u[7]);
        r4[2*j]     = a;
        r4[2*j + 1] = bv;
        m = fmaxf(m, fmaxf(fmaxf(a.x, a.y), fmaxf(a.z, a.w)));
        m = fmaxf(m, fmaxf(fmaxf(bv.x, bv.y), fmaxf(bv.z, bv.w)));
    }
#pragma unroll
    for (int off = 32; off > 0; off >>= 1) m = fmaxf(m, __shfl_xor(m, off));
    if ((tid & 63) == 0) red[tid >> 6] = m;
    __syncthreads();
    m = fmaxf(fmaxf(red[0], red[1]), fmaxf(red[2], red[3]));

    const float invw = 1.f / W_, invh = 1.f / H_;
    float s = 0.f, sx = 0.f, sy = 0.f;
    for (int j = tid; j < HW/4; j += 256) {
        float4 u = r4[j];
        int e0 = j * 4;
        int h  = e0 / W_;
        int w0 = e0 - h * W_;
        float y  = (2*h + 1) * invh - 1.f;
        float x0 = (2*w0 + 1) * invw - 1.f;
        float4 e;
        e.x = __expf(u.x - m); s += e.x; sy = fmaf(e.x, y, sy); sx = fmaf(e.x, x0,          sx);
        e.y = __expf(u.y - m); s += e.y; sy = fmaf(e.y, y, sy); sx = fmaf(e.y, x0 + 2*invw, sx);
        e.z = __expf(u.z - m); s += e.z; sy = fmaf(e.z, y, sy); sx = fmaf(e.z, x0 + 4*invw, sx);
        e.w = __expf(u.w - m); s += e.w; sy = fmaf(e.w, y, sy); sx = fmaf(e.w, x0 + 6*invw, sx);
        r4[j] = e;                               // store unnormalized exp
    }
#pragma unroll
    for (int off = 32; off > 0; off >>= 1) {
        s  += __shfl_xor(s,  off);
        sx += __shfl_xor(sx, off);
        sy += __shfl_xor(sy, off);
    }
    if ((tid & 63) == 0) { int w = tid >> 6; red[4+w] = s; red[8+w] = sx; red[12+w] = sy; }
    __syncthreads();
    s  = red[4] + red[5] + red[6]  + red[7];
    sx = red[8] + red[9] + red[10] + red[11];
    sy = red[12] + red[13] + red[14] + red[15];
    float inv = 1.f / s;

    for (int j = tid; j < HW/4; j += 256) {
        float4 e = r4[j];
        e.x *= inv; e.y *= inv; e.z *= inv; e.w *= inv;
        out4[j] = e;
    }
    if (tid == 0) {
        coords[row*2 + 0] = sx * inv;
        coords[row*2 + 1] = sy * inv;
    }
}

// ------------------------------------------------------------------------------
extern "C" void kernel_launch(void* const* d_in, const int* in_sizes, int n_in,
                              void* d_out, int out_size, void* d_ws, size_t ws_size,
                              hipStream_t stream) {
    const float* fcn = (const float*)d_in[0];
    const float* hmw = (const float*)d_in[1];
    const float* dww = (const float*)d_in[2];
    const float* fuw = (const float*)d_in[3];
    float* out = (float*)d_out;
    char* ws = (char*)d_ws;

    size_t off = 0;
    unsigned short* wfrag = (unsigned short*)(ws + off); off += 131072;          // 128 KB
    float*          buf1  = (float*)         (ws + off); off += 41943040;        // 42 MB (unnorm)
    unsigned short* abf   = (unsigned short*)(ws + off); off += 20971520;        // 21 MB (A bf16)
    float*          part  = (float*)         (ws + off); off += (size_t)NCH*16*4096*4; // 4 MB
    unsigned short* rfrag = (unsigned short*)(ws + off); off += 262144;          // 256 KB
    unsigned short* tbuf  = (unsigned short*)(ws + off); off += 20971520;        // 21 MB (t bf16)

    float* hm2            = out + 4096;   // final heatmaps (fp32)
    float* final_coords   = out;
    float* interme_coords = out + 2048;

    hipLaunchKernelGGL(k_prep_w,            dim3(256),      dim3(256), 0, stream, hmw, wfrag);
    hipLaunchKernelGGL(k_gemm1_mfma,        dim3(40, 16),   dim3(512), 0, stream, fcn, wfrag, buf1);
    hipLaunchKernelGGL(k_softmax_dsnt_conv, dim3(1024),     dim3(256), 0, stream, buf1, dww, abf, interme_coords);
    hipLaunchKernelGGL(k_rel_partial,       dim3(NCH, 16),  dim3(256), 0, stream, abf, part);
    hipLaunchKernelGGL(k_rel_finalize,      dim3(16),       dim3(256), 0, stream, part, rfrag);
    hipLaunchKernelGGL(k_feate_mfma,        dim3(80, 16),   dim3(256), 0, stream, abf, rfrag, fuw, tbuf);
    hipLaunchKernelGGL(k_softmax_dsnt,      dim3(1024),     dim3(256), 0, stream, tbuf, hm2, final_coords);
}

// Round 16
// 178.673 us; speedup vs baseline: 1.9636x; 1.0904x over previous
//
#include <hip/hip_runtime.h>

#define B_  16
#define CIN 512
#define C_  64
#define H_  64
#define W_  160
#define HW  (H_*W_)   // 10240
#define NCH 16        // relation hw-chunks per batch (640 hw each)

typedef __attribute__((ext_vector_type(8))) short bf16x8;
typedef __attribute__((ext_vector_type(4))) float f32x4;
typedef __attribute__((ext_vector_type(8))) unsigned short u16x8;
typedef __attribute__((ext_vector_type(4))) unsigned short u16x4;

// RNE float -> bf16
__device__ inline unsigned short f2bf(float x) {
    unsigned u = __float_as_uint(x);
    return (unsigned short)((u + 0x7FFF + ((u >> 16) & 1)) >> 16);
}
__device__ inline float bf2f(unsigned short v) {
    return __uint_as_float((unsigned)v << 16);
}

// RNE float -> bf16 hi, then RNE bf16 of the remainder (weight prep)
__device__ inline void bf16_split(float x, unsigned short& h, unsigned short& l) {
    h = f2bf(x);
    float lo = x - bf2f(h);
    l = f2bf(lo);
}

// Truncation split (gemm1 hot path)
__device__ inline void bf16_tsplit(float x, short& h, short& l) {
    unsigned u = __float_as_uint(x);
    h = (short)(u >> 16);
    float hf = __uint_as_float(u & 0xFFFF0000u);
    float lo = x - hf;
    l = (short)(__float_as_uint(lo) >> 16);
}

// ---------------- K1: pack hm_w into MFMA-fragment-ordered hi/lo bf16 ---------
// o = t*16 + (lane&15), k = ks*32 + (lane>>4)*8 + j   (A-operand layout)
__global__ __launch_bounds__(256) void k_prep_w(const float* __restrict__ hmw,
                                                unsigned short* __restrict__ wfrag) {
    int tid  = blockIdx.x * 256 + threadIdx.x;        // 0 .. 65535
    int j    = tid & 7;
    int lane = (tid >> 3) & 63;
    int t    = (tid >> 9) & 3;
    int p    = (tid >> 11) & 1;
    int ks   = tid >> 12;
    int o = t * 16 + (lane & 15);
    int k = ks * 32 + ((lane >> 4) << 3) + j;
    float val = hmw[o * CIN + k];
    unsigned short h, l;
    bf16_split(val, h, l);
    wfrag[tid] = p ? l : h;
}

// ---------------- K2: unnorm = fcn x W via bf16 hi/lo MFMA --------------------
// Counted-vmcnt pipeline (T3/T4 minimal recipe): x-tile AND w-tile staged via
// global_load_lds (only VMEM in the loop), raw s_barrier + inline-asm
// s_waitcnt vmcnt(5) so next-step loads STAY IN FLIGHT across the barrier
// (default __syncthreads drains vmcnt(0) and kills the prefetch).
__global__ __launch_bounds__(512, 4) void k_gemm1_mfma(const float* __restrict__ fcn,
                                                       const unsigned short* __restrict__ wfrag,
                                                       float* __restrict__ out) {
    const int lane  = threadIdx.x & 63;
    const int wv    = threadIdx.x >> 6;               // 0..7
    const int b     = blockIdx.y;
    const int pxblk = blockIdx.x * 256;               // block's 256-px window

    __shared__ float xs[2][32 * 256];                 // 2 x 32 KB x-tiles
    __shared__ unsigned short wsh[2][4096];           // 2 x 8 KB w-tiles

    const int chl  = (lane >> 4) << 3;
    const int pxw  = wv * 32;
    const int px16 = lane & 15;

    const size_t gbase = (size_t)b * CIN * HW + pxblk + (lane << 2);
    const int    grow0 = wv << 2;
    const int    lbase = grow0 * 256;

    // 5 VMEM ops per wave per step: 4 x-rows (1 KB each) + 1 w-chunk (1 KB)
#define STAGE(buf, ks)                                                                  \
    {                                                                                   \
        _Pragma("unroll")                                                               \
        for (int i = 0; i < 4; ++i) {                                                   \
            const float* g = fcn + gbase + (size_t)((ks) * 32 + grow0 + i) * HW;        \
            float* l = &xs[(buf)][lbase + i * 256];                                     \
            __builtin_amdgcn_global_load_lds(                                           \
                (const __attribute__((address_space(1))) void*)g,                       \
                (__attribute__((address_space(3))) void*)l, 16, 0, 0);                  \
        }                                                                               \
        {                                                                               \
            const unsigned short* g = wfrag + (ks) * 4096 + wv * 512 + lane * 8;        \
            unsigned short* l = &wsh[(buf)][wv * 512];                                  \
            __builtin_amdgcn_global_load_lds(                                           \
                (const __attribute__((address_space(1))) void*)g,                       \
                (__attribute__((address_space(3))) void*)l, 16, 0, 0);                  \
        }                                                                               \
    }

    f32x4 acc[2][4];
#pragma unroll
    for (int xt = 0; xt < 2; ++xt)
#pragma unroll
        for (int t = 0; t < 4; ++t) acc[xt][t] = (f32x4)0.f;

    // one K-step of fragment loads + MFMA from buffer `bb`
#define COMPUTE(bb)                                                                     \
    {                                                                                   \
        float xa[8], xb[8];                                                             \
        _Pragma("unroll")                                                               \
        for (int j = 0; j < 8; ++j) {                                                   \
            const float* r = &xs[(bb)][(chl + j) * 256 + pxw + px16];                   \
            xa[j] = r[0];                                                               \
            xb[j] = r[16];                                                              \
        }                                                                               \
        bf16x8 xah, xal, xbh, xbl;                                                      \
        _Pragma("unroll")                                                               \
        for (int j = 0; j < 8; ++j) {                                                   \
            short h, l;                                                                 \
            bf16_tsplit(xa[j], h, l);                                                   \
            xah[j] = h; xal[j] = l;                                                     \
            bf16_tsplit(xb[j], h, l);                                                   \
            xbh[j] = h; xbl[j] = l;                                                     \
        }                                                                               \
        const unsigned short* wk = &wsh[(bb)][0];                                       \
        bf16x8 wh = *reinterpret_cast<const bf16x8*>(wk + (lane << 3));                 \
        bf16x8 wl = *reinterpret_cast<const bf16x8*>(wk + ((4 * 64 + lane) << 3));      \
        _Pragma("unroll")                                                               \
        for (int t = 0; t < 4; ++t) {                                                   \
            bf16x8 whn, wln;                                                            \
            if (t < 3) {                                                                \
                whn = *reinterpret_cast<const bf16x8*>(wk + (((t + 1) * 64 + lane) << 3)); \
                wln = *reinterpret_cast<const bf16x8*>(wk + (((5 + t) * 64 + lane) << 3)); \
            }                                                                           \
            acc[0][t] = __builtin_amdgcn_mfma_f32_16x16x32_bf16(wh, xah, acc[0][t], 0, 0, 0); \
            acc[0][t] = __builtin_amdgcn_mfma_f32_16x16x32_bf16(wh, xal, acc[0][t], 0, 0, 0); \
            acc[0][t] = __builtin_amdgcn_mfma_f32_16x16x32_bf16(wl, xah, acc[0][t], 0, 0, 0); \
            acc[1][t] = __builtin_amdgcn_mfma_f32_16x16x32_bf16(wh, xbh, acc[1][t], 0, 0, 0); \
            acc[1][t] = __builtin_amdgcn_mfma_f32_16x16x32_bf16(wh, xbl, acc[1][t], 0, 0, 0); \
            acc[1][t] = __builtin_amdgcn_mfma_f32_16x16x32_bf16(wl, xbh, acc[1][t], 0, 0, 0); \
            wh = whn; wl = wln;                                                         \
        }                                                                               \
    }

    STAGE(0, 0);
    asm volatile("s_waitcnt vmcnt(0)" ::: "memory");
    __builtin_amdgcn_sched_barrier(0);
    __builtin_amdgcn_s_barrier();

    int cur = 0;
#pragma unroll 1
    for (int ks = 0; ks < 15; ++ks) {
        STAGE(cur ^ 1, ks + 1);                       // issue next tile (stays in flight)
        asm volatile("s_waitcnt vmcnt(5)" ::: "memory");  // own step-ks loads complete
        __builtin_amdgcn_sched_barrier(0);
        __builtin_amdgcn_s_barrier();                 // all waves' step-ks loads landed
        COMPUTE(cur);
        __builtin_amdgcn_s_barrier();                 // done reading cur (overwritten next iter)
        cur ^= 1;
    }
    // final step: drain remaining loads, compute
    asm volatile("s_waitcnt vmcnt(0)" ::: "memory");
    __builtin_amdgcn_sched_barrier(0);
    __builtin_amdgcn_s_barrier();
    COMPUTE(cur);
#undef STAGE
#undef COMPUTE

    // ---- store: D col = lane&15 (px), row = (lane>>4)*4 + reg (o in tile) ----
    const int orow = (lane >> 4) << 2;
    float* __restrict__ op = out + (size_t)b * C_ * HW + pxblk + pxw + px16;
#pragma unroll
    for (int xt = 0; xt < 2; ++xt)
#pragma unroll
        for (int t = 0; t < 4; ++t)
#pragma unroll
            for (int reg = 0; reg < 4; ++reg)
                op[(size_t)(t * 16 + orow + reg) * HW + xt * 16] = acc[xt][t][reg];
}

// ------- K3: softmax + dsnt + FUSED depthwise conv; A written as bf16 ---------
__global__ __launch_bounds__(256) void k_softmax_dsnt_conv(const float* __restrict__ in0,
                                                           const float* __restrict__ dw,
                                                           unsigned short* __restrict__ aout,
                                                           float* __restrict__ coords) {
    const int row = blockIdx.x;                  // b*64 + c
    const int c   = row & (C_ - 1);
    const int tid = threadIdx.x;
    const float4* in04 = reinterpret_cast<const float4*>(in0 + (size_t)row * HW);
    __shared__ float rowbuf[HW];                 // 40 KB (unnorm -> exp)
    __shared__ float red[16];
    float4* r4 = reinterpret_cast<float4*>(rowbuf);

    float m = -3.402823466e38f;
    for (int j = tid; j < HW/4; j += 256) {
        float4 u = in04[j];
        r4[j] = u;
        m = fmaxf(m, fmaxf(fmaxf(u.x, u.y), fmaxf(u.z, u.w)));
    }
#pragma unroll
    for (int off = 32; off > 0; off >>= 1) m = fmaxf(m, __shfl_xor(m, off));
    if ((tid & 63) == 0) red[tid >> 6] = m;
    __syncthreads();
    m = fmaxf(fmaxf(red[0], red[1]), fmaxf(red[2], red[3]));

    const float invw = 1.f / W_, invh = 1.f / H_;
    float s = 0.f, sx = 0.f, sy = 0.f;
    for (int j = tid; j < HW/4; j += 256) {
        float4 u = r4[j];
        int e0 = j * 4;
        int h  = e0 / W_;
        int w0 = e0 - h * W_;
        float y  = (2*h + 1) * invh - 1.f;
        float x0 = (2*w0 + 1) * invw - 1.f;
        float4 e;
        e.x = __expf(u.x - m); s += e.x; sy = fmaf(e.x, y, sy); sx = fmaf(e.x, x0,          sx);
        e.y = __expf(u.y - m); s += e.y; sy = fmaf(e.y, y, sy); sx = fmaf(e.y, x0 + 2*invw, sx);
        e.z = __expf(u.z - m); s += e.z; sy = fmaf(e.z, y, sy); sx = fmaf(e.z, x0 + 4*invw, sx);
        e.w = __expf(u.w - m); s += e.w; sy = fmaf(e.w, y, sy); sx = fmaf(e.w, x0 + 6*invw, sx);
        r4[j] = e;                               // store unnormalized exp
    }
#pragma unroll
    for (int off = 32; off > 0; off >>= 1) {
        s  += __shfl_xor(s,  off);
        sx += __shfl_xor(sx, off);
        sy += __shfl_xor(sy, off);
    }
    if ((tid & 63) == 0) { int w = tid >> 6; red[4+w] = s; red[8+w] = sx; red[12+w] = sy; }
    __syncthreads();                             // also fences all r4 writes
    s  = red[4] + red[5] + red[6]  + red[7];
    sx = red[8] + red[9] + red[10] + red[11];
    sy = red[12] + red[13] + red[14] + red[15];
    float inv = 1.f / s;

    if (tid == 0) {
        coords[row*2 + 0] = sx * inv;
        coords[row*2 + 1] = sy * inv;
    }

    float wv[25];
#pragma unroll
    for (int k = 0; k < 25; ++k) wv[k] = dw[c * 25 + k];

    u16x4* aout4 = reinterpret_cast<u16x4*>(aout + (size_t)row * HW);
    for (int j = tid; j < HW/4; j += 256) {
        int h  = j / (W_/4);
        int w4 = j - h * (W_/4);
        int w4m = (w4 > 0) ? w4 - 1 : 0;
        int w4p = (w4 < W_/4 - 1) ? w4 + 1 : W_/4 - 1;
        float a0 = 0.f, a1 = 0.f, a2 = 0.f, a3 = 0.f;
#pragma unroll
        for (int dy = 0; dy < 5; ++dy) {
            int rr = h + dy - 2;
            bool rok = (rr >= 0) && (rr < H_);
            int rc = rok ? rr : 0;
            const float4* rp = reinterpret_cast<const float4*>(rowbuf + rc * W_);
            float4 L = rp[w4m];
            float4 M = rp[w4];
            float4 R = rp[w4p];
            float f[12];
            f[0]=L.x; f[1]=L.y; f[2]=L.z; f[3]=L.w;
            f[4]=M.x; f[5]=M.y; f[6]=M.z; f[7]=M.w;
            f[8]=R.x; f[9]=R.y; f[10]=R.z; f[11]=R.w;
            if (!rok) {
#pragma unroll
                for (int q = 0; q < 12; ++q) f[q] = 0.f;
            }
            if (w4 == 0)          { f[0]=f[1]=f[2]=f[3] = 0.f; }
            if (w4 == W_/4 - 1)   { f[8]=f[9]=f[10]=f[11] = 0.f; }
            const float* wr = wv + dy * 5;
#pragma unroll
            for (int dx = 0; dx < 5; ++dx) {
                float wt = wr[dx];
                a0 = fmaf(f[2 + 0 + dx], wt, a0);
                a1 = fmaf(f[2 + 1 + dx], wt, a1);
                a2 = fmaf(f[2 + 2 + dx], wt, a2);
                a3 = fmaf(f[2 + 3 + dx], wt, a3);
            }
        }
        u16x4 ov;
        ov[0] = f2bf(a0 * inv); ov[1] = f2bf(a1 * inv);
        ov[2] = f2bf(a2 * inv); ov[3] = f2bf(a3 * inv);
        aout4[j] = ov;
    }
}

// ------- K5: relation partials A·A^T via MFMA (no LDS, no barriers) -----------
__global__ __launch_bounds__(256) void k_rel_partial(const unsigned short* __restrict__ A,
                                                     float* __restrict__ part) {
    const int b  = blockIdx.y, ch = blockIdx.x;
    const int lane = threadIdx.x & 63;
    const int w    = threadIdx.x >> 6;          // wave's cg (0..3)
    const int hwb  = ch * (HW / NCH);           // 640-hw chunk
    const unsigned short* __restrict__ ab = A + (size_t)b * C_ * HW;
    const int r16 = lane & 15, h8 = (lane >> 4) << 3;
    const unsigned short* __restrict__ own = ab + (size_t)(w * 16 + r16) * HW;

    f32x4 acc[4];
#pragma unroll
    for (int d = 0; d < 4; ++d) acc[d] = (f32x4)0.f;

#pragma unroll 1
    for (int kk = 0; kk < (HW / NCH) / 32; ++kk) {
        const int hw0 = hwb + kk * 32 + h8;
        bf16x8 fra = *reinterpret_cast<const bf16x8*>(own + hw0);
#pragma unroll
        for (int d = 0; d < 4; ++d) {
            bf16x8 frb = *reinterpret_cast<const bf16x8*>(ab + (size_t)(d * 16 + r16) * HW + hw0);
            acc[d] = __builtin_amdgcn_mfma_f32_16x16x32_bf16(fra, frb, acc[d], 0, 0, 0);
        }
    }

    float* __restrict__ pp = part + (size_t)(b * NCH + ch) * 4096;
    const int crow = w * 16 + ((lane >> 4) << 2);
#pragma unroll
    for (int d = 0; d < 4; ++d)
#pragma unroll
        for (int reg = 0; reg < 4; ++reg)
            pp[(crow + reg) * 64 + d * 16 + r16] = acc[d][reg];
}

// ------ K6: reduce partials, rowmax-sub softmax, pack R as MFMA frags ---------
__global__ __launch_bounds__(256) void k_rel_finalize(const float* __restrict__ part,
                                                      unsigned short* __restrict__ rfrag) {
    const int b = blockIdx.x;
    __shared__ float rel[64][65];
    __shared__ float Rs[64][64];
    for (int e = threadIdx.x; e < 4096; e += 256) {
        float s = 0.f;
        for (int k = 0; k < NCH; ++k) s += part[(size_t)(b * NCH + k) * 4096 + e];
        rel[e >> 6][e & 63] = s;
    }
    __syncthreads();
    if (threadIdx.x < 64) {
        int cc = threadIdx.x;
        // softmax(rowmax - r) == exp(rowmin - r) / sum(exp(rowmin - r))
        float mn = rel[cc][0];
        for (int d = 1; d < 64; ++d) mn = fminf(mn, rel[cc][d]);
        float s = 0.f;
        for (int d = 0; d < 64; ++d) s += __expf(mn - rel[cc][d]);
        float inv = 1.f / s;
        for (int d = 0; d < 64; ++d)
            Rs[cc][d] = __expf(mn - rel[cc][d]) * inv;
    }
    __syncthreads();
    unsigned short* __restrict__ rb = rfrag + (size_t)b * 8192;
    for (int idx = threadIdx.x; idx < 1024; idx += 256) {
        int lane = idx & 63;
        int rest = idx >> 6;          // ks*8 + p*4 + t
        int t  = rest & 3;
        int p  = (rest >> 2) & 1;
        int ks = rest >> 3;
        int o  = t * 16 + (lane & 15);
        int d0 = ks * 32 + ((lane >> 4) << 3);
        bf16x8 v;
#pragma unroll
        for (int j = 0; j < 8; ++j) {
            unsigned short h, l;
            bf16_split(Rs[o][d0 + j], h, l);
            v[j] = (short)(p ? l : h);
        }
        *reinterpret_cast<bf16x8*>(rb + idx * 8) = v;
    }
}

// ------- K7: feat_e = R·A (A single bf16, R hi/lo); t=(fe+A)*fu -> bf16 -------
__global__ __launch_bounds__(256, 4) void k_feate_mfma(const unsigned short* __restrict__ A,
                                                       const unsigned short* __restrict__ rfrag,
                                                       const float* __restrict__ fu,
                                                       unsigned short* __restrict__ tout) {
    const int lane = threadIdx.x & 63;
    const int wv   = threadIdx.x >> 6;
    const int b    = blockIdx.y;
    const int px0  = blockIdx.x * 128 + wv * 32;

    const int pxa = px0 + (lane & 15);
    const int chl = (lane >> 4) << 3;
    const unsigned short* __restrict__ apx = A + ((size_t)b * C_ + chl) * HW + pxa;
    const unsigned short* __restrict__ rp = rfrag + (size_t)b * 8192 + lane * 8;

    f32x4 acc[2][4];
#pragma unroll
    for (int xt = 0; xt < 2; ++xt)
#pragma unroll
        for (int t = 0; t < 4; ++t) acc[xt][t] = (f32x4)0.f;

#pragma unroll 1
    for (int ks = 0; ks < 2; ++ks) {
        bf16x8 xa, xb;
#pragma unroll
        for (int j = 0; j < 8; ++j) {
            const unsigned short* p0 = apx + (size_t)(ks * 32 + j) * HW;
            xa[j] = (short)p0[0];
            xb[j] = (short)p0[16];
        }
        const unsigned short* __restrict__ rk = rp + (size_t)ks * 8 * 512;
        bf16x8 rh = *reinterpret_cast<const bf16x8*>(rk);
        bf16x8 rl = *reinterpret_cast<const bf16x8*>(rk + 4 * 512);
#pragma unroll
        for (int t = 0; t < 4; ++t) {
            bf16x8 rhn, rln;
            if (t < 3) {
                rhn = *reinterpret_cast<const bf16x8*>(rk + (t + 1) * 512);
                rln = *reinterpret_cast<const bf16x8*>(rk + (4 + t + 1) * 512);
            }
            acc[0][t] = __builtin_amdgcn_mfma_f32_16x16x32_bf16(rh, xa, acc[0][t], 0, 0, 0);
            acc[0][t] = __builtin_amdgcn_mfma_f32_16x16x32_bf16(rl, xa, acc[0][t], 0, 0, 0);
            acc[1][t] = __builtin_amdgcn_mfma_f32_16x16x32_bf16(rh, xb, acc[1][t], 0, 0, 0);
            acc[1][t] = __builtin_amdgcn_mfma_f32_16x16x32_bf16(rl, xb, acc[1][t], 0, 0, 0);
            rh = rhn; rl = rln;
        }
    }

    // epilogue: t = (feat_e + A) * fu, write bf16
    const int orow = (lane >> 4) << 2;
    const unsigned short* __restrict__ ares = A + (size_t)b * C_ * HW + px0 + (lane & 15);
    unsigned short* __restrict__ op        = tout + (size_t)b * C_ * HW + px0 + (lane & 15);
#pragma unroll
    for (int xt = 0; xt < 2; ++xt)
#pragma unroll
        for (int t = 0; t < 4; ++t)
#pragma unroll
            for (int reg = 0; reg < 4; ++reg) {
                const int oc = t * 16 + orow + reg;
                float r = acc[xt][t][reg] + bf2f(ares[(size_t)oc * HW + xt * 16]);
                op[(size_t)oc * HW + xt * 16] = f2bf(r * fu[oc]);
            }
}

// ---------------- K8: row softmax (bf16 input) + dsnt; fp32 heatmap out -------
__global__ __launch_bounds__(256) void k_softmax_dsnt(const unsigned short* __restrict__ in0,
                                                      float* __restrict__ pout,
                                                      float* __restrict__ coords) {
    const int row = blockIdx.x;                  // b*64 + c
    const int tid = threadIdx.x;
    const u16x8* in08 = reinterpret_cast<const u16x8*>(in0 + (size_t)row * HW);
    float4*      out4 = reinterpret_cast<float4*>(pout + (size_t)row * HW);
    __shared__ float rowbuf[HW];                 // 40 KB
    __shared__ float red[16];
    float4* r4 = reinterpret_cast<float4*>(rowbuf);

    float m = -3.402823466e38f;
    for (int j = tid; j < HW/8; j += 256) {
        u16x8 u = in08[j];
        float4 a, bv;
        a.x  = bf2f(u[0]); a.y  = bf2f(u[1]); a.z  = bf2f(u[2]); a.w  = bf2f(u[3]);
        bv.x = bf2f(u[4]); bv.y = bf2f(u[5]); bv.z = bf2f(u[6]); bv.w = bf2f(u[7]);
        r4[2*j]     = a;
        r4[2*j + 1] = bv;
        m = fmaxf(m, fmaxf(fmaxf(a.x, a.y), fmaxf(a.z, a.w)));
        m = fmaxf(m, fmaxf(fmaxf(bv.x, bv.y), fmaxf(bv.z, bv.w)));
    }
#pragma unroll
    for (int off = 32; off > 0; off >>= 1) m = fmaxf(m, __shfl_xor(m, off));
    if ((tid & 63) == 0) red[tid >> 6] = m;
    __syncthreads();
    m = fmaxf(fmaxf(red[0], red[1]), fmaxf(red[2], red[3]));

    const float invw = 1.f / W_, invh = 1.f / H_;
    float s = 0.f, sx = 0.f, sy = 0.f;
    for (int j = tid; j < HW/4; j += 256) {
        float4 u = r4[j];
        int e0 = j * 4;
        int h  = e0 / W_;
        int w0 = e0 - h * W_;
        float y  = (2*h + 1) * invh - 1.f;
        float x0 = (2*w0 + 1) * invw - 1.f;
        float4 e;
        e.x = __expf(u.x - m); s += e.x; sy = fmaf(e.x, y, sy); sx = fmaf(e.x, x0,          sx);
        e.y = __expf(u.y - m); s += e.y; sy = fmaf(e.y, y, sy); sx = fmaf(e.y, x0 + 2*invw, sx);
        e.z = __expf(u.z - m); s += e.z; sy = fmaf(e.z, y, sy); sx = fmaf(e.z, x0 + 4*invw, sx);
        e.w = __expf(u.w - m); s += e.w; sy = fmaf(e.w, y, sy); sx = fmaf(e.w, x0 + 6*invw, sx);
        r4[j] = e;                               // store unnormalized exp
    }
#pragma unroll
    for (int off = 32; off > 0; off >>= 1) {
        s  += __shfl_xor(s,  off);
        sx += __shfl_xor(sx, off);
        sy += __shfl_xor(sy, off);
    }
    if ((tid & 63) == 0) { int w = tid >> 6; red[4+w] = s; red[8+w] = sx; red[12+w] = sy; }
    __syncthreads();
    s  = red[4] + red[5] + red[6]  + red[7];
    sx = red[8] + red[9] + red[10] + red[11];
    sy = red[12] + red[13] + red[14] + red[15];
    float inv = 1.f / s;

    for (int j = tid; j < HW/4; j += 256) {
        float4 e = r4[j];
        e.x *= inv; e.y *= inv; e.z *= inv; e.w *= inv;
        out4[j] = e;
    }
    if (tid == 0) {
        coords[row*2 + 0] = sx * inv;
        coords[row*2 + 1] = sy * inv;
    }
}

// ------------------------------------------------------------------------------
extern "C" void kernel_launch(void* const* d_in, const int* in_sizes, int n_in,
                              void* d_out, int out_size, void* d_ws, size_t ws_size,
                              hipStream_t stream) {
    const float* fcn = (const float*)d_in[0];
    const float* hmw = (const float*)d_in[1];
    const float* dww = (const float*)d_in[2];
    const float* fuw = (const float*)d_in[3];
    float* out = (float*)d_out;
    char* ws = (char*)d_ws;

    size_t off = 0;
    unsigned short* wfrag = (unsigned short*)(ws + off); off += 131072;          // 128 KB
    float*          buf1  = (float*)         (ws + off); off += 41943040;        // 42 MB (unnorm)
    unsigned short* abf   = (unsigned short*)(ws + off); off += 20971520;        // 21 MB (A bf16)
    float*          part  = (float*)         (ws + off); off += (size_t)NCH*16*4096*4; // 4 MB
    unsigned short* rfrag = (unsigned short*)(ws + off); off += 262144;          // 256 KB
    unsigned short* tbuf  = (unsigned short*)(ws + off); off += 20971520;        // 21 MB (t bf16)

    float* hm2            = out + 4096;   // final heatmaps (fp32)
    float* final_coords   = out;
    float* interme_coords = out + 2048;

    hipLaunchKernelGGL(k_prep_w,            dim3(256),      dim3(256), 0, stream, hmw, wfrag);
    hipLaunchKernelGGL(k_gemm1_mfma,        dim3(40, 16),   dim3(512), 0, stream, fcn, wfrag, buf1);
    hipLaunchKernelGGL(k_softmax_dsnt_conv, dim3(1024),     dim3(256), 0, stream, buf1, dww, abf, interme_coords);
    hipLaunchKernelGGL(k_rel_partial,       dim3(NCH, 16),  dim3(256), 0, stream, abf, part);
    hipLaunchKernelGGL(k_rel_finalize,      dim3(16),       dim3(256), 0, stream, part, rfrag);
    hipLaunchKernelGGL(k_feate_mfma,        dim3(80, 16),   dim3(256), 0, stream, abf, rfrag, fuw, tbuf);
    hipLaunchKernelGGL(k_softmax_dsnt,      dim3(1024),     dim3(256), 0, stream, tbuf, hm2, final_coords);
}

// Round 17
// 173.283 us; speedup vs baseline: 2.0246x; 1.0311x over previous
//
#include <hip/hip_runtime.h>

#define B_  16
#define CIN 512
#define C_  64
#define H_  64
#define W_  160
#define HW  (H_*W_)   // 10240
#define NCH 16        // relation hw-chunks per batch (640 hw each)

typedef __attribute__((ext_vector_type(8))) short bf16x8;
typedef __attribute__((ext_vector_type(4))) float f32x4;
typedef __attribute__((ext_vector_type(8))) unsigned short u16x8;
typedef __attribute__((ext_vector_type(4))) unsigned short u16x4;

// RNE float -> bf16
__device__ inline unsigned short f2bf(float x) {
    unsigned u = __float_as_uint(x);
    return (unsigned short)((u + 0x7FFF + ((u >> 16) & 1)) >> 16);
}
__device__ inline float bf2f(unsigned short v) {
    return __uint_as_float((unsigned)v << 16);
}

// RNE float -> bf16 hi, then RNE bf16 of the remainder (weight prep)
__device__ inline void bf16_split(float x, unsigned short& h, unsigned short& l) {
    h = f2bf(x);
    float lo = x - bf2f(h);
    l = f2bf(lo);
}

// Truncation split (gemm1 hot path)
__device__ inline void bf16_tsplit(float x, short& h, short& l) {
    unsigned u = __float_as_uint(x);
    h = (short)(u >> 16);
    float hf = __uint_as_float(u & 0xFFFF0000u);
    float lo = x - hf;
    l = (short)(__float_as_uint(lo) >> 16);
}

// ---------------- K1: pack hm_w into MFMA-fragment-ordered hi/lo bf16 ---------
__global__ __launch_bounds__(256) void k_prep_w(const float* __restrict__ hmw,
                                                unsigned short* __restrict__ wfrag) {
    int tid  = blockIdx.x * 256 + threadIdx.x;        // 0 .. 65535
    int j    = tid & 7;
    int lane = (tid >> 3) & 63;
    int t    = (tid >> 9) & 3;
    int p    = (tid >> 11) & 1;
    int ks   = tid >> 12;
    int o = t * 16 + (lane & 15);
    int k = ks * 32 + ((lane >> 4) << 3) + j;
    float val = hmw[o * CIN + k];
    unsigned short h, l;
    bf16_split(val, h, l);
    wfrag[tid] = p ? l : h;
}

// ---------------- K2: unnorm = fcn x W via bf16 hi/lo MFMA --------------------
// Counted-vmcnt pipeline (verified R16: ~79 us): x-tile AND w-tile staged via
// global_load_lds (only VMEM in the loop), raw s_barrier + counted vmcnt(5)
// so next-step loads stay in flight across the barrier.
__global__ __launch_bounds__(512, 4) void k_gemm1_mfma(const float* __restrict__ fcn,
                                                       const unsigned short* __restrict__ wfrag,
                                                       float* __restrict__ out) {
    const int lane  = threadIdx.x & 63;
    const int wv    = threadIdx.x >> 6;               // 0..7
    const int b     = blockIdx.y;
    const int pxblk = blockIdx.x * 256;               // block's 256-px window

    __shared__ float xs[2][32 * 256];                 // 2 x 32 KB x-tiles
    __shared__ unsigned short wsh[2][4096];           // 2 x 8 KB w-tiles

    const int chl  = (lane >> 4) << 3;
    const int pxw  = wv * 32;
    const int px16 = lane & 15;

    const size_t gbase = (size_t)b * CIN * HW + pxblk + (lane << 2);
    const int    grow0 = wv << 2;
    const int    lbase = grow0 * 256;

#define STAGE(buf, ks)                                                                  \
    {                                                                                   \
        _Pragma("unroll")                                                               \
        for (int i = 0; i < 4; ++i) {                                                   \
            const float* g = fcn + gbase + (size_t)((ks) * 32 + grow0 + i) * HW;        \
            float* l = &xs[(buf)][lbase + i * 256];                                     \
            __builtin_amdgcn_global_load_lds(                                           \
                (const __attribute__((address_space(1))) void*)g,                       \
                (__attribute__((address_space(3))) void*)l, 16, 0, 0);                  \
        }                                                                               \
        {                                                                               \
            const unsigned short* g = wfrag + (ks) * 4096 + wv * 512 + lane * 8;        \
            unsigned short* l = &wsh[(buf)][wv * 512];                                  \
            __builtin_amdgcn_global_load_lds(                                           \
                (const __attribute__((address_space(1))) void*)g,                       \
                (__attribute__((address_space(3))) void*)l, 16, 0, 0);                  \
        }                                                                               \
    }

    f32x4 acc[2][4];
#pragma unroll
    for (int xt = 0; xt < 2; ++xt)
#pragma unroll
        for (int t = 0; t < 4; ++t) acc[xt][t] = (f32x4)0.f;

#define COMPUTE(bb)                                                                     \
    {                                                                                   \
        float xa[8], xb[8];                                                             \
        _Pragma("unroll")                                                               \
        for (int j = 0; j < 8; ++j) {                                                   \
            const float* r = &xs[(bb)][(chl + j) * 256 + pxw + px16];                   \
            xa[j] = r[0];                                                               \
            xb[j] = r[16];                                                              \
        }                                                                               \
        bf16x8 xah, xal, xbh, xbl;                                                      \
        _Pragma("unroll")                                                               \
        for (int j = 0; j < 8; ++j) {                                                   \
            short h, l;                                                                 \
            bf16_tsplit(xa[j], h, l);                                                   \
            xah[j] = h; xal[j] = l;                                                     \
            bf16_tsplit(xb[j], h, l);                                                   \
            xbh[j] = h; xbl[j] = l;                                                     \
        }                                                                               \
        const unsigned short* wk = &wsh[(bb)][0];                                       \
        bf16x8 wh = *reinterpret_cast<const bf16x8*>(wk + (lane << 3));                 \
        bf16x8 wl = *reinterpret_cast<const bf16x8*>(wk + ((4 * 64 + lane) << 3));      \
        _Pragma("unroll")                                                               \
        for (int t = 0; t < 4; ++t) {                                                   \
            bf16x8 whn, wln;                                                            \
            if (t < 3) {                                                                \
                whn = *reinterpret_cast<const bf16x8*>(wk + (((t + 1) * 64 + lane) << 3)); \
                wln = *reinterpret_cast<const bf16x8*>(wk + (((5 + t) * 64 + lane) << 3)); \
            }                                                                           \
            acc[0][t] = __builtin_amdgcn_mfma_f32_16x16x32_bf16(wh, xah, acc[0][t], 0, 0, 0); \
            acc[0][t] = __builtin_amdgcn_mfma_f32_16x16x32_bf16(wh, xal, acc[0][t], 0, 0, 0); \
            acc[0][t] = __builtin_amdgcn_mfma_f32_16x16x32_bf16(wl, xah, acc[0][t], 0, 0, 0); \
            acc[1][t] = __builtin_amdgcn_mfma_f32_16x16x32_bf16(wh, xbh, acc[1][t], 0, 0, 0); \
            acc[1][t] = __builtin_amdgcn_mfma_f32_16x16x32_bf16(wh, xbl, acc[1][t], 0, 0, 0); \
            acc[1][t] = __builtin_amdgcn_mfma_f32_16x16x32_bf16(wl, xbh, acc[1][t], 0, 0, 0); \
            wh = whn; wl = wln;                                                         \
        }                                                                               \
    }

    STAGE(0, 0);
    asm volatile("s_waitcnt vmcnt(0)" ::: "memory");
    __builtin_amdgcn_sched_barrier(0);
    __builtin_amdgcn_s_barrier();

    int cur = 0;
#pragma unroll 1
    for (int ks = 0; ks < 15; ++ks) {
        STAGE(cur ^ 1, ks + 1);                       // issue next tile (stays in flight)
        asm volatile("s_waitcnt vmcnt(5)" ::: "memory");  // own step-ks loads complete
        __builtin_amdgcn_sched_barrier(0);
        __builtin_amdgcn_s_barrier();                 // all waves' step-ks loads landed
        COMPUTE(cur);
        __builtin_amdgcn_s_barrier();                 // done reading cur (overwritten next iter)
        cur ^= 1;
    }
    asm volatile("s_waitcnt vmcnt(0)" ::: "memory");
    __builtin_amdgcn_sched_barrier(0);
    __builtin_amdgcn_s_barrier();
    COMPUTE(cur);
#undef STAGE
#undef COMPUTE

    const int orow = (lane >> 4) << 2;
    float* __restrict__ op = out + (size_t)b * C_ * HW + pxblk + pxw + px16;
#pragma unroll
    for (int xt = 0; xt < 2; ++xt)
#pragma unroll
        for (int t = 0; t < 4; ++t)
#pragma unroll
            for (int reg = 0; reg < 4; ++reg)
                op[(size_t)(t * 16 + orow + reg) * HW + xt * 16] = acc[xt][t][reg];
}

// ------- K3: softmax + dsnt + FUSED depthwise conv; A written as bf16 ---------
// 512 threads (8 waves) per row: halves the VALU-bound per-row latency.
__global__ __launch_bounds__(512) void k_softmax_dsnt_conv(const float* __restrict__ in0,
                                                           const float* __restrict__ dw,
                                                           unsigned short* __restrict__ aout,
                                                           float* __restrict__ coords) {
    const int row = blockIdx.x;                  // b*64 + c
    const int c   = row & (C_ - 1);
    const int tid = threadIdx.x;
    const float4* in04 = reinterpret_cast<const float4*>(in0 + (size_t)row * HW);
    __shared__ float rowbuf[HW];                 // 40 KB (unnorm -> exp)
    __shared__ float red[32];
    float4* r4 = reinterpret_cast<float4*>(rowbuf);

    float m = -3.402823466e38f;
    for (int j = tid; j < HW/4; j += 512) {
        float4 u = in04[j];
        r4[j] = u;
        m = fmaxf(m, fmaxf(fmaxf(u.x, u.y), fmaxf(u.z, u.w)));
    }
#pragma unroll
    for (int off = 32; off > 0; off >>= 1) m = fmaxf(m, __shfl_xor(m, off));
    if ((tid & 63) == 0) red[tid >> 6] = m;
    __syncthreads();
#pragma unroll
    for (int q = 1; q < 8; ++q) m = fmaxf(m, red[q]);
    m = fmaxf(m, red[0]);

    const float invw = 1.f / W_, invh = 1.f / H_;
    float s = 0.f, sx = 0.f, sy = 0.f;
    for (int j = tid; j < HW/4; j += 512) {
        float4 u = r4[j];
        int e0 = j * 4;
        int h  = e0 / W_;
        int w0 = e0 - h * W_;
        float y  = (2*h + 1) * invh - 1.f;
        float x0 = (2*w0 + 1) * invw - 1.f;
        float4 e;
        e.x = __expf(u.x - m); s += e.x; sy = fmaf(e.x, y, sy); sx = fmaf(e.x, x0,          sx);
        e.y = __expf(u.y - m); s += e.y; sy = fmaf(e.y, y, sy); sx = fmaf(e.y, x0 + 2*invw, sx);
        e.z = __expf(u.z - m); s += e.z; sy = fmaf(e.z, y, sy); sx = fmaf(e.z, x0 + 4*invw, sx);
        e.w = __expf(u.w - m); s += e.w; sy = fmaf(e.w, y, sy); sx = fmaf(e.w, x0 + 6*invw, sx);
        r4[j] = e;                               // store unnormalized exp
    }
#pragma unroll
    for (int off = 32; off > 0; off >>= 1) {
        s  += __shfl_xor(s,  off);
        sx += __shfl_xor(sx, off);
        sy += __shfl_xor(sy, off);
    }
    if ((tid & 63) == 0) { int w = tid >> 6; red[8+w] = s; red[16+w] = sx; red[24+w] = sy; }
    __syncthreads();                             // also fences all r4 writes
    s = 0.f; sx = 0.f; sy = 0.f;
#pragma unroll
    for (int q = 0; q < 8; ++q) { s += red[8+q]; sx += red[16+q]; sy += red[24+q]; }
    float inv = 1.f / s;

    if (tid == 0) {
        coords[row*2 + 0] = sx * inv;
        coords[row*2 + 1] = sy * inv;
    }

    float wv[25];
#pragma unroll
    for (int k = 0; k < 25; ++k) wv[k] = dw[c * 25 + k];

    u16x4* aout4 = reinterpret_cast<u16x4*>(aout + (size_t)row * HW);
    for (int j = tid; j < HW/4; j += 512) {
        int h  = j / (W_/4);
        int w4 = j - h * (W_/4);
        int w4m = (w4 > 0) ? w4 - 1 : 0;
        int w4p = (w4 < W_/4 - 1) ? w4 + 1 : W_/4 - 1;
        float a0 = 0.f, a1 = 0.f, a2 = 0.f, a3 = 0.f;
#pragma unroll
        for (int dy = 0; dy < 5; ++dy) {
            int rr = h + dy - 2;
            bool rok = (rr >= 0) && (rr < H_);
            int rc = rok ? rr : 0;
            const float4* rp = reinterpret_cast<const float4*>(rowbuf + rc * W_);
            float4 L = rp[w4m];
            float4 M = rp[w4];
            float4 R = rp[w4p];
            float f[12];
            f[0]=L.x; f[1]=L.y; f[2]=L.z; f[3]=L.w;
            f[4]=M.x; f[5]=M.y; f[6]=M.z; f[7]=M.w;
            f[8]=R.x; f[9]=R.y; f[10]=R.z; f[11]=R.w;
            if (!rok) {
#pragma unroll
                for (int q = 0; q < 12; ++q) f[q] = 0.f;
            }
            if (w4 == 0)          { f[0]=f[1]=f[2]=f[3] = 0.f; }
            if (w4 == W_/4 - 1)   { f[8]=f[9]=f[10]=f[11] = 0.f; }
            const float* wr = wv + dy * 5;
#pragma unroll
            for (int dx = 0; dx < 5; ++dx) {
                float wt = wr[dx];
                a0 = fmaf(f[2 + 0 + dx], wt, a0);
                a1 = fmaf(f[2 + 1 + dx], wt, a1);
                a2 = fmaf(f[2 + 2 + dx], wt, a2);
                a3 = fmaf(f[2 + 3 + dx], wt, a3);
            }
        }
        u16x4 ov;
        ov[0] = f2bf(a0 * inv); ov[1] = f2bf(a1 * inv);
        ov[2] = f2bf(a2 * inv); ov[3] = f2bf(a3 * inv);
        aout4[j] = ov;
    }
}

// ------- K5: relation partials A·A^T via MFMA (no LDS, no barriers) -----------
__global__ __launch_bounds__(256) void k_rel_partial(const unsigned short* __restrict__ A,
                                                     float* __restrict__ part) {
    const int b  = blockIdx.y, ch = blockIdx.x;
    const int lane = threadIdx.x & 63;
    const int w    = threadIdx.x >> 6;          // wave's cg (0..3)
    const int hwb  = ch * (HW / NCH);           // 640-hw chunk
    const unsigned short* __restrict__ ab = A + (size_t)b * C_ * HW;
    const int r16 = lane & 15, h8 = (lane >> 4) << 3;
    const unsigned short* __restrict__ own = ab + (size_t)(w * 16 + r16) * HW;

    f32x4 acc[4];
#pragma unroll
    for (int d = 0; d < 4; ++d) acc[d] = (f32x4)0.f;

#pragma unroll 1
    for (int kk = 0; kk < (HW / NCH) / 32; ++kk) {
        const int hw0 = hwb + kk * 32 + h8;
        bf16x8 fra = *reinterpret_cast<const bf16x8*>(own + hw0);
#pragma unroll
        for (int d = 0; d < 4; ++d) {
            bf16x8 frb = *reinterpret_cast<const bf16x8*>(ab + (size_t)(d * 16 + r16) * HW + hw0);
            acc[d] = __builtin_amdgcn_mfma_f32_16x16x32_bf16(fra, frb, acc[d], 0, 0, 0);
        }
    }

    float* __restrict__ pp = part + (size_t)(b * NCH + ch) * 4096;
    const int crow = w * 16 + ((lane >> 4) << 2);
#pragma unroll
    for (int d = 0; d < 4; ++d)
#pragma unroll
        for (int reg = 0; reg < 4; ++reg)
            pp[(crow + reg) * 64 + d * 16 + r16] = acc[d][reg];
}

// ------ K6: reduce partials, rowmax-sub softmax, pack R as MFMA frags ---------
__global__ __launch_bounds__(256) void k_rel_finalize(const float* __restrict__ part,
                                                      unsigned short* __restrict__ rfrag) {
    const int b = blockIdx.x;
    __shared__ float rel[64][65];
    __shared__ float Rs[64][64];
    for (int e = threadIdx.x; e < 4096; e += 256) {
        float s = 0.f;
        for (int k = 0; k < NCH; ++k) s += part[(size_t)(b * NCH + k) * 4096 + e];
        rel[e >> 6][e & 63] = s;
    }
    __syncthreads();
    if (threadIdx.x < 64) {
        int cc = threadIdx.x;
        // softmax(rowmax - r) == exp(rowmin - r) / sum(exp(rowmin - r))
        float mn = rel[cc][0];
        for (int d = 1; d < 64; ++d) mn = fminf(mn, rel[cc][d]);
        float s = 0.f;
        for (int d = 0; d < 64; ++d) s += __expf(mn - rel[cc][d]);
        float inv = 1.f / s;
        for (int d = 0; d < 64; ++d)
            Rs[cc][d] = __expf(mn - rel[cc][d]) * inv;
    }
    __syncthreads();
    unsigned short* __restrict__ rb = rfrag + (size_t)b * 8192;
    for (int idx = threadIdx.x; idx < 1024; idx += 256) {
        int lane = idx & 63;
        int rest = idx >> 6;          // ks*8 + p*4 + t
        int t  = rest & 3;
        int p  = (rest >> 2) & 1;
        int ks = rest >> 3;
        int o  = t * 16 + (lane & 15);
        int d0 = ks * 32 + ((lane >> 4) << 3);
        bf16x8 v;
#pragma unroll
        for (int j = 0; j < 8; ++j) {
            unsigned short h, l;
            bf16_split(Rs[o][d0 + j], h, l);
            v[j] = (short)(p ? l : h);
        }
        *reinterpret_cast<bf16x8*>(rb + idx * 8) = v;
    }
}

// ------- K7: feat_e = R·A (A single bf16, R hi/lo); t=(fe+A)*fu -> bf16 -------
// (256,5): 5 blocks/CU -> capacity 1280 == grid, no straggler wave.
__global__ __launch_bounds__(256, 5) void k_feate_mfma(const unsigned short* __restrict__ A,
                                                       const unsigned short* __restrict__ rfrag,
                                                       const float* __restrict__ fu,
                                                       unsigned short* __restrict__ tout) {
    const int lane = threadIdx.x & 63;
    const int wv   = threadIdx.x >> 6;
    const int b    = blockIdx.y;
    const int px0  = blockIdx.x * 128 + wv * 32;

    const int pxa = px0 + (lane & 15);
    const int chl = (lane >> 4) << 3;
    const unsigned short* __restrict__ apx = A + ((size_t)b * C_ + chl) * HW + pxa;
    const unsigned short* __restrict__ rp = rfrag + (size_t)b * 8192 + lane * 8;

    f32x4 acc[2][4];
#pragma unroll
    for (int xt = 0; xt < 2; ++xt)
#pragma unroll
        for (int t = 0; t < 4; ++t) acc[xt][t] = (f32x4)0.f;

#pragma unroll 1
    for (int ks = 0; ks < 2; ++ks) {
        bf16x8 xa, xb;
#pragma unroll
        for (int j = 0; j < 8; ++j) {
            const unsigned short* p0 = apx + (size_t)(ks * 32 + j) * HW;
            xa[j] = (short)p0[0];
            xb[j] = (short)p0[16];
        }
        const unsigned short* __restrict__ rk = rp + (size_t)ks * 8 * 512;
        bf16x8 rh = *reinterpret_cast<const bf16x8*>(rk);
        bf16x8 rl = *reinterpret_cast<const bf16x8*>(rk + 4 * 512);
#pragma unroll
        for (int t = 0; t < 4; ++t) {
            bf16x8 rhn, rln;
            if (t < 3) {
                rhn = *reinterpret_cast<const bf16x8*>(rk + (t + 1) * 512);
                rln = *reinterpret_cast<const bf16x8*>(rk + (4 + t + 1) * 512);
            }
            acc[0][t] = __builtin_amdgcn_mfma_f32_16x16x32_bf16(rh, xa, acc[0][t], 0, 0, 0);
            acc[0][t] = __builtin_amdgcn_mfma_f32_16x16x32_bf16(rl, xa, acc[0][t], 0, 0, 0);
            acc[1][t] = __builtin_amdgcn_mfma_f32_16x16x32_bf16(rh, xb, acc[1][t], 0, 0, 0);
            acc[1][t] = __builtin_amdgcn_mfma_f32_16x16x32_bf16(rl, xb, acc[1][t], 0, 0, 0);
            rh = rhn; rl = rln;
        }
    }

    // epilogue: t = (feat_e + A) * fu, write bf16
    const int orow = (lane >> 4) << 2;
    const unsigned short* __restrict__ ares = A + (size_t)b * C_ * HW + px0 + (lane & 15);
    unsigned short* __restrict__ op        = tout + (size_t)b * C_ * HW + px0 + (lane & 15);
#pragma unroll
    for (int xt = 0; xt < 2; ++xt)
#pragma unroll
        for (int t = 0; t < 4; ++t)
#pragma unroll
            for (int reg = 0; reg < 4; ++reg) {
                const int oc = t * 16 + orow + reg;
                float r = acc[xt][t][reg] + bf2f(ares[(size_t)oc * HW + xt * 16]);
                op[(size_t)oc * HW + xt * 16] = f2bf(r * fu[oc]);
            }
}

// ---------------- K8: row softmax (bf16 input) + dsnt; fp32 heatmap out -------
// 512 threads (8 waves) per row.
__global__ __launch_bounds__(512) void k_softmax_dsnt(const unsigned short* __restrict__ in0,
                                                      float* __restrict__ pout,
                                                      float* __restrict__ coords) {
    const int row = blockIdx.x;                  // b*64 + c
    const int tid = threadIdx.x;
    const u16x8* in08 = reinterpret_cast<const u16x8*>(in0 + (size_t)row * HW);
    float4*      out4 = reinterpret_cast<float4*>(pout + (size_t)row * HW);
    __shared__ float rowbuf[HW];                 // 40 KB
    __shared__ float red[32];
    float4* r4 = reinterpret_cast<float4*>(rowbuf);

    float m = -3.402823466e38f;
    for (int j = tid; j < HW/8; j += 512) {
        u16x8 u = in08[j];
        float4 a, bv;
        a.x  = bf2f(u[0]); a.y  = bf2f(u[1]); a.z  = bf2f(u[2]); a.w  = bf2f(u[3]);
        bv.x = bf2f(u[4]); bv.y = bf2f(u[5]); bv.z = bf2f(u[6]); bv.w = bf2f(u[7]);
        r4[2*j]     = a;
        r4[2*j + 1] = bv;
        m = fmaxf(m, fmaxf(fmaxf(a.x, a.y), fmaxf(a.z, a.w)));
        m = fmaxf(m, fmaxf(fmaxf(bv.x, bv.y), fmaxf(bv.z, bv.w)));
    }
#pragma unroll
    for (int off = 32; off > 0; off >>= 1) m = fmaxf(m, __shfl_xor(m, off));
    if ((tid & 63) == 0) red[tid >> 6] = m;
    __syncthreads();
#pragma unroll
    for (int q = 0; q < 8; ++q) m = fmaxf(m, red[q]);

    const float invw = 1.f / W_, invh = 1.f / H_;
    float s = 0.f, sx = 0.f, sy = 0.f;
    for (int j = tid; j < HW/4; j += 512) {
        float4 u = r4[j];
        int e0 = j * 4;
        int h  = e0 / W_;
        int w0 = e0 - h * W_;
        float y  = (2*h + 1) * invh - 1.f;
        float x0 = (2*w0 + 1) * invw - 1.f;
        float4 e;
        e.x = __expf(u.x - m); s += e.x; sy = fmaf(e.x, y, sy); sx = fmaf(e.x, x0,          sx);
        e.y = __expf(u.y - m); s += e.y; sy = fmaf(e.y, y, sy); sx = fmaf(e.y, x0 + 2*invw, sx);
        e.z = __expf(u.z - m); s += e.z; sy = fmaf(e.z, y, sy); sx = fmaf(e.z, x0 + 4*invw, sx);
        e.w = __expf(u.w - m); s += e.w; sy = fmaf(e.w, y, sy); sx = fmaf(e.w, x0 + 6*invw, sx);
        r4[j] = e;                               // store unnormalized exp
    }
#pragma unroll
    for (int off = 32; off > 0; off >>= 1) {
        s  += __shfl_xor(s,  off);
        sx += __shfl_xor(sx, off);
        sy += __shfl_xor(sy, off);
    }
    if ((tid & 63) == 0) { int w = tid >> 6; red[8+w] = s; red[16+w] = sx; red[24+w] = sy; }
    __syncthreads();
    s = 0.f; sx = 0.f; sy = 0.f;
#pragma unroll
    for (int q = 0; q < 8; ++q) { s += red[8+q]; sx += red[16+q]; sy += red[24+q]; }
    float inv = 1.f / s;

    for (int j = tid; j < HW/4; j += 512) {
        float4 e = r4[j];
        e.x *= inv; e.y *= inv; e.z *= inv; e.w *= inv;
        out4[j] = e;
    }
    if (tid == 0) {
        coords[row*2 + 0] = sx * inv;
        coords[row*2 + 1] = sy * inv;
    }
}

// ------------------------------------------------------------------------------
extern "C" void kernel_launch(void* const* d_in, const int* in_sizes, int n_in,
                              void* d_out, int out_size, void* d_ws, size_t ws_size,
                              hipStream_t stream) {
    const float* fcn = (const float*)d_in[0];
    const float* hmw = (const float*)d_in[1];
    const float* dww = (const float*)d_in[2];
    const float* fuw = (const float*)d_in[3];
    float* out = (float*)d_out;
    char* ws = (char*)d_ws;

    size_t off = 0;
    unsigned short* wfrag = (unsigned short*)(ws + off); off += 131072;          // 128 KB
    float*          buf1  = (float*)         (ws + off); off += 41943040;        // 42 MB (unnorm)
    unsigned short* abf   = (unsigned short*)(ws + off); off += 20971520;        // 21 MB (A bf16)
    float*          part  = (float*)         (ws + off); off += (size_t)NCH*16*4096*4; // 4 MB
    unsigned short* rfrag = (unsigned short*)(ws + off); off += 262144;          // 256 KB
    unsigned short* tbuf  = (unsigned short*)(ws + off); off += 20971520;        // 21 MB (t bf16)

    float* hm2            = out + 4096;   // final heatmaps (fp32)
    float* final_coords   = out;
    float* interme_coords = out + 2048;

    hipLaunchKernelGGL(k_prep_w,            dim3(256),      dim3(256), 0, stream, hmw, wfrag);
    hipLaunchKernelGGL(k_gemm1_mfma,        dim3(40, 16),   dim3(512), 0, stream, fcn, wfrag, buf1);
    hipLaunchKernelGGL(k_softmax_dsnt_conv, dim3(1024),     dim3(512), 0, stream, buf1, dww, abf, interme_coords);
    hipLaunchKernelGGL(k_rel_partial,       dim3(NCH, 16),  dim3(256), 0, stream, abf, part);
    hipLaunchKernelGGL(k_rel_finalize,      dim3(16),       dim3(256), 0, stream, part, rfrag);
    hipLaunchKernelGGL(k_feate_mfma,        dim3(80, 16),   dim3(256), 0, stream, abf, rfrag, fuw, tbuf);
    hipLaunchKernelGGL(k_softmax_dsnt,      dim3(1024),     dim3(512), 0, stream, tbuf, hm2, final_coords);
}

// Round 18
// 166.535 us; speedup vs baseline: 2.1067x; 1.0405x over previous
//
#include <hip/hip_runtime.h>

#define B_  16
#define CIN 512
#define C_  64
#define H_  64
#define W_  160
#define HW  (H_*W_)   // 10240
#define NCH 16        // relation hw-chunks per batch (640 hw each)

typedef __attribute__((ext_vector_type(8))) short bf16x8;
typedef __attribute__((ext_vector_type(4))) float f32x4;
typedef __attribute__((ext_vector_type(8))) unsigned short u16x8;
typedef __attribute__((ext_vector_type(4))) unsigned short u16x4;

// RNE float -> bf16
__device__ inline unsigned short f2bf(float x) {
    unsigned u = __float_as_uint(x);
    return (unsigned short)((u + 0x7FFF + ((u >> 16) & 1)) >> 16);
}
__device__ inline float bf2f(unsigned short v) {
    return __uint_as_float((unsigned)v << 16);
}

// RNE float -> bf16 hi, then RNE bf16 of the remainder (weight prep)
__device__ inline void bf16_split(float x, unsigned short& h, unsigned short& l) {
    h = f2bf(x);
    float lo = x - bf2f(h);
    l = f2bf(lo);
}

// Truncation split (gemm1 hot path)
__device__ inline void bf16_tsplit(float x, short& h, short& l) {
    unsigned u = __float_as_uint(x);
    h = (short)(u >> 16);
    float hf = __uint_as_float(u & 0xFFFF0000u);
    float lo = x - hf;
    l = (short)(__float_as_uint(lo) >> 16);
}

// ---------------- K1: pack hm_w into MFMA-fragment-ordered hi/lo bf16 ---------
__global__ __launch_bounds__(256) void k_prep_w(const float* __restrict__ hmw,
                                                unsigned short* __restrict__ wfrag) {
    int tid  = blockIdx.x * 256 + threadIdx.x;        // 0 .. 65535
    int j    = tid & 7;
    int lane = (tid >> 3) & 63;
    int t    = (tid >> 9) & 3;
    int p    = (tid >> 11) & 1;
    int ks   = tid >> 12;
    int o = t * 16 + (lane & 15);
    int k = ks * 32 + ((lane >> 4) << 3) + j;
    float val = hmw[o * CIN + k];
    unsigned short h, l;
    bf16_split(val, h, l);
    wfrag[tid] = p ? l : h;
}

// ---------------- K2: unnorm = fcn x W via bf16 hi/lo MFMA --------------------
// Counted-vmcnt pipeline (verified R16: ~79 us).
__global__ __launch_bounds__(512, 4) void k_gemm1_mfma(const float* __restrict__ fcn,
                                                       const unsigned short* __restrict__ wfrag,
                                                       float* __restrict__ out) {
    const int lane  = threadIdx.x & 63;
    const int wv    = threadIdx.x >> 6;               // 0..7
    const int b     = blockIdx.y;
    const int pxblk = blockIdx.x * 256;               // block's 256-px window

    __shared__ float xs[2][32 * 256];                 // 2 x 32 KB x-tiles
    __shared__ unsigned short wsh[2][4096];           // 2 x 8 KB w-tiles

    const int chl  = (lane >> 4) << 3;
    const int pxw  = wv * 32;
    const int px16 = lane & 15;

    const size_t gbase = (size_t)b * CIN * HW + pxblk + (lane << 2);
    const int    grow0 = wv << 2;
    const int    lbase = grow0 * 256;

#define STAGE(buf, ks)                                                                  \
    {                                                                                   \
        _Pragma("unroll")                                                               \
        for (int i = 0; i < 4; ++i) {                                                   \
            const float* g = fcn + gbase + (size_t)((ks) * 32 + grow0 + i) * HW;        \
            float* l = &xs[(buf)][lbase + i * 256];                                     \
            __builtin_amdgcn_global_load_lds(                                           \
                (const __attribute__((address_space(1))) void*)g,                       \
                (__attribute__((address_space(3))) void*)l, 16, 0, 0);                  \
        }                                                                               \
        {                                                                               \
            const unsigned short* g = wfrag + (ks) * 4096 + wv * 512 + lane * 8;        \
            unsigned short* l = &wsh[(buf)][wv * 512];                                  \
            __builtin_amdgcn_global_load_lds(                                           \
                (const __attribute__((address_space(1))) void*)g,                       \
                (__attribute__((address_space(3))) void*)l, 16, 0, 0);                  \
        }                                                                               \
    }

    f32x4 acc[2][4];
#pragma unroll
    for (int xt = 0; xt < 2; ++xt)
#pragma unroll
        for (int t = 0; t < 4; ++t) acc[xt][t] = (f32x4)0.f;

#define COMPUTE(bb)                                                                     \
    {                                                                                   \
        float xa[8], xb[8];                                                             \
        _Pragma("unroll")                                                               \
        for (int j = 0; j < 8; ++j) {                                                   \
            const float* r = &xs[(bb)][(chl + j) * 256 + pxw + px16];                   \
            xa[j] = r[0];                                                               \
            xb[j] = r[16];                                                              \
        }                                                                               \
        bf16x8 xah, xal, xbh, xbl;                                                      \
        _Pragma("unroll")                                                               \
        for (int j = 0; j < 8; ++j) {                                                   \
            short h, l;                                                                 \
            bf16_tsplit(xa[j], h, l);                                                   \
            xah[j] = h; xal[j] = l;                                                     \
            bf16_tsplit(xb[j], h, l);                                                   \
            xbh[j] = h; xbl[j] = l;                                                     \
        }                                                                               \
        const unsigned short* wk = &wsh[(bb)][0];                                       \
        bf16x8 wh = *reinterpret_cast<const bf16x8*>(wk + (lane << 3));                 \
        bf16x8 wl = *reinterpret_cast<const bf16x8*>(wk + ((4 * 64 + lane) << 3));      \
        _Pragma("unroll")                                                               \
        for (int t = 0; t < 4; ++t) {                                                   \
            bf16x8 whn, wln;                                                            \
            if (t < 3) {                                                                \
                whn = *reinterpret_cast<const bf16x8*>(wk + (((t + 1) * 64 + lane) << 3)); \
                wln = *reinterpret_cast<const bf16x8*>(wk + (((5 + t) * 64 + lane) << 3)); \
            }                                                                           \
            acc[0][t] = __builtin_amdgcn_mfma_f32_16x16x32_bf16(wh, xah, acc[0][t], 0, 0, 0); \
            acc[0][t] = __builtin_amdgcn_mfma_f32_16x16x32_bf16(wh, xal, acc[0][t], 0, 0, 0); \
            acc[0][t] = __builtin_amdgcn_mfma_f32_16x16x32_bf16(wl, xah, acc[0][t], 0, 0, 0); \
            acc[1][t] = __builtin_amdgcn_mfma_f32_16x16x32_bf16(wh, xbh, acc[1][t], 0, 0, 0); \
            acc[1][t] = __builtin_amdgcn_mfma_f32_16x16x32_bf16(wh, xbl, acc[1][t], 0, 0, 0); \
            acc[1][t] = __builtin_amdgcn_mfma_f32_16x16x32_bf16(wl, xbh, acc[1][t], 0, 0, 0); \
            wh = whn; wl = wln;                                                         \
        }                                                                               \
    }

    STAGE(0, 0);
    asm volatile("s_waitcnt vmcnt(0)" ::: "memory");
    __builtin_amdgcn_sched_barrier(0);
    __builtin_amdgcn_s_barrier();

    int cur = 0;
#pragma unroll 1
    for (int ks = 0; ks < 15; ++ks) {
        STAGE(cur ^ 1, ks + 1);                       // issue next tile (stays in flight)
        asm volatile("s_waitcnt vmcnt(5)" ::: "memory");  // own step-ks loads complete
        __builtin_amdgcn_sched_barrier(0);
        __builtin_amdgcn_s_barrier();                 // all waves' step-ks loads landed
        COMPUTE(cur);
        __builtin_amdgcn_s_barrier();                 // done reading cur (overwritten next iter)
        cur ^= 1;
    }
    asm volatile("s_waitcnt vmcnt(0)" ::: "memory");
    __builtin_amdgcn_sched_barrier(0);
    __builtin_amdgcn_s_barrier();
    COMPUTE(cur);
#undef STAGE
#undef COMPUTE

    const int orow = (lane >> 4) << 2;
    float* __restrict__ op = out + (size_t)b * C_ * HW + pxblk + pxw + px16;
#pragma unroll
    for (int xt = 0; xt < 2; ++xt)
#pragma unroll
        for (int t = 0; t < 4; ++t)
#pragma unroll
            for (int reg = 0; reg < 4; ++reg)
                op[(size_t)(t * 16 + orow + reg) * HW + xt * 16] = acc[xt][t][reg];
}

// ------- K3: softmax + dsnt + FUSED depthwise conv; A written as bf16 ---------
// 512 threads / row. Conv phase: sliding-window — thread = (image row, 20-px
// segment); 7 b128 window loads per dy (2.1x fewer LDS reads than per-4px).
__global__ __launch_bounds__(512) void k_softmax_dsnt_conv(const float* __restrict__ in0,
                                                           const float* __restrict__ dw,
                                                           unsigned short* __restrict__ aout,
                                                           float* __restrict__ coords) {
    const int row = blockIdx.x;                  // b*64 + c
    const int c   = row & (C_ - 1);
    const int tid = threadIdx.x;
    const float4* in04 = reinterpret_cast<const float4*>(in0 + (size_t)row * HW);
    __shared__ float rowbuf[HW];                 // 40 KB (unnorm -> exp)
    __shared__ float red[32];
    float4* r4 = reinterpret_cast<float4*>(rowbuf);

    float m = -3.402823466e38f;
    for (int j = tid; j < HW/4; j += 512) {
        float4 u = in04[j];
        r4[j] = u;
        m = fmaxf(m, fmaxf(fmaxf(u.x, u.y), fmaxf(u.z, u.w)));
    }
#pragma unroll
    for (int off = 32; off > 0; off >>= 1) m = fmaxf(m, __shfl_xor(m, off));
    if ((tid & 63) == 0) red[tid >> 6] = m;
    __syncthreads();
#pragma unroll
    for (int q = 0; q < 8; ++q) m = fmaxf(m, red[q]);

    const float invw = 1.f / W_, invh = 1.f / H_;
    float s = 0.f, sx = 0.f, sy = 0.f;
    for (int j = tid; j < HW/4; j += 512) {
        float4 u = r4[j];
        int e0 = j * 4;
        int h  = e0 / W_;
        int w0 = e0 - h * W_;
        float y  = (2*h + 1) * invh - 1.f;
        float x0 = (2*w0 + 1) * invw - 1.f;
        float4 e;
        e.x = __expf(u.x - m); s += e.x; sy = fmaf(e.x, y, sy); sx = fmaf(e.x, x0,          sx);
        e.y = __expf(u.y - m); s += e.y; sy = fmaf(e.y, y, sy); sx = fmaf(e.y, x0 + 2*invw, sx);
        e.z = __expf(u.z - m); s += e.z; sy = fmaf(e.z, y, sy); sx = fmaf(e.z, x0 + 4*invw, sx);
        e.w = __expf(u.w - m); s += e.w; sy = fmaf(e.w, y, sy); sx = fmaf(e.w, x0 + 6*invw, sx);
        r4[j] = e;                               // store unnormalized exp
    }
#pragma unroll
    for (int off = 32; off > 0; off >>= 1) {
        s  += __shfl_xor(s,  off);
        sx += __shfl_xor(sx, off);
        sy += __shfl_xor(sy, off);
    }
    if ((tid & 63) == 0) { int w = tid >> 6; red[8+w] = s; red[16+w] = sx; red[24+w] = sy; }
    __syncthreads();                             // also fences all r4 writes
    s = 0.f; sx = 0.f; sy = 0.f;
#pragma unroll
    for (int q = 0; q < 8; ++q) { s += red[8+q]; sx += red[16+q]; sy += red[24+q]; }
    float inv = 1.f / s;

    if (tid == 0) {
        coords[row*2 + 0] = sx * inv;
        coords[row*2 + 1] = sy * inv;
    }

    float wv[25];
#pragma unroll
    for (int k = 0; k < 25; ++k) wv[k] = dw[c * 25 + k];

    // ---- conv phase: thread -> (image row ir, 20-px segment sg) ----
    const int ir = tid >> 3;                     // 0..63
    const int sg = tid & 7;                      // 0..7
    float a20[20];
#pragma unroll
    for (int p = 0; p < 20; ++p) a20[p] = 0.f;
#pragma unroll
    for (int dy = 0; dy < 5; ++dy) {
        int rr = ir + dy - 2;
        if (rr < 0 || rr >= H_) continue;
        const float4* rp = reinterpret_cast<const float4*>(rowbuf + rr * W_);
        float w28[28];
#pragma unroll
        for (int q = 0; q < 7; ++q) {
            int f4i = sg * 5 - 1 + q;
            if (f4i >= 0 && f4i < 40) {
                float4 v = rp[f4i];
                w28[q*4+0] = v.x; w28[q*4+1] = v.y; w28[q*4+2] = v.z; w28[q*4+3] = v.w;
            } else {
                w28[q*4+0] = 0.f; w28[q*4+1] = 0.f; w28[q*4+2] = 0.f; w28[q*4+3] = 0.f;
            }
        }
        const float* wr = wv + dy * 5;
#pragma unroll
        for (int dx = 0; dx < 5; ++dx) {
            float wt = wr[dx];
#pragma unroll
            for (int p = 0; p < 20; ++p)
                a20[p] = fmaf(w28[p + 2 + dx], wt, a20[p]);
        }
    }
    unsigned short* ao = aout + (size_t)row * HW + ir * W_ + sg * 20;
#pragma unroll
    for (int k4 = 0; k4 < 5; ++k4) {
        u16x4 ov;
        ov[0] = f2bf(a20[k4*4+0] * inv);
        ov[1] = f2bf(a20[k4*4+1] * inv);
        ov[2] = f2bf(a20[k4*4+2] * inv);
        ov[3] = f2bf(a20[k4*4+3] * inv);
        *reinterpret_cast<u16x4*>(ao + k4 * 4) = ov;
    }
}

// ------- K5: relation partials A·A^T via MFMA (no LDS, no barriers) -----------
__global__ __launch_bounds__(256) void k_rel_partial(const unsigned short* __restrict__ A,
                                                     float* __restrict__ part) {
    const int b  = blockIdx.y, ch = blockIdx.x;
    const int lane = threadIdx.x & 63;
    const int w    = threadIdx.x >> 6;          // wave's cg (0..3)
    const int hwb  = ch * (HW / NCH);           // 640-hw chunk
    const unsigned short* __restrict__ ab = A + (size_t)b * C_ * HW;
    const int r16 = lane & 15, h8 = (lane >> 4) << 3;
    const unsigned short* __restrict__ own = ab + (size_t)(w * 16 + r16) * HW;

    f32x4 acc[4];
#pragma unroll
    for (int d = 0; d < 4; ++d) acc[d] = (f32x4)0.f;

#pragma unroll 1
    for (int kk = 0; kk < (HW / NCH) / 32; ++kk) {
        const int hw0 = hwb + kk * 32 + h8;
        bf16x8 fra = *reinterpret_cast<const bf16x8*>(own + hw0);
#pragma unroll
        for (int d = 0; d < 4; ++d) {
            bf16x8 frb = *reinterpret_cast<const bf16x8*>(ab + (size_t)(d * 16 + r16) * HW + hw0);
            acc[d] = __builtin_amdgcn_mfma_f32_16x16x32_bf16(fra, frb, acc[d], 0, 0, 0);
        }
    }

    float* __restrict__ pp = part + (size_t)(b * NCH + ch) * 4096;
    const int crow = w * 16 + ((lane >> 4) << 2);
#pragma unroll
    for (int d = 0; d < 4; ++d)
#pragma unroll
        for (int reg = 0; reg < 4; ++reg)
            pp[(crow + reg) * 64 + d * 16 + r16] = acc[d][reg];
}

// ------ K6: reduce partials, rowmax-sub softmax, pack R as MFMA frags ---------
__global__ __launch_bounds__(256) void k_rel_finalize(const float* __restrict__ part,
                                                      unsigned short* __restrict__ rfrag) {
    const int b = blockIdx.x;
    __shared__ float rel[64][65];
    __shared__ float Rs[64][64];
    for (int e = threadIdx.x; e < 4096; e += 256) {
        float s = 0.f;
        for (int k = 0; k < NCH; ++k) s += part[(size_t)(b * NCH + k) * 4096 + e];
        rel[e >> 6][e & 63] = s;
    }
    __syncthreads();
    if (threadIdx.x < 64) {
        int cc = threadIdx.x;
        // softmax(rowmax - r) == exp(rowmin - r) / sum(exp(rowmin - r))
        float mn = rel[cc][0];
        for (int d = 1; d < 64; ++d) mn = fminf(mn, rel[cc][d]);
        float s = 0.f;
        for (int d = 0; d < 64; ++d) s += __expf(mn - rel[cc][d]);
        float inv = 1.f / s;
        for (int d = 0; d < 64; ++d)
            Rs[cc][d] = __expf(mn - rel[cc][d]) * inv;
    }
    __syncthreads();
    unsigned short* __restrict__ rb = rfrag + (size_t)b * 8192;
    for (int idx = threadIdx.x; idx < 1024; idx += 256) {
        int lane = idx & 63;
        int rest = idx >> 6;          // ks*8 + p*4 + t
        int t  = rest & 3;
        int p  = (rest >> 2) & 1;
        int ks = rest >> 3;
        int o  = t * 16 + (lane & 15);
        int d0 = ks * 32 + ((lane >> 4) << 3);
        bf16x8 v;
#pragma unroll
        for (int j = 0; j < 8; ++j) {
            unsigned short h, l;
            bf16_split(Rs[o][d0 + j], h, l);
            v[j] = (short)(p ? l : h);
        }
        *reinterpret_cast<bf16x8*>(rb + idx * 8) = v;
    }
}

// ------- K7: feat_e = R·A (A single bf16, R hi/lo); t=(fe+A)*fu -> bf16 -------
__global__ __launch_bounds__(256, 5) void k_feate_mfma(const unsigned short* __restrict__ A,
                                                       const unsigned short* __restrict__ rfrag,
                                                       const float* __restrict__ fu,
                                                       unsigned short* __restrict__ tout) {
    const int lane = threadIdx.x & 63;
    const int wv   = threadIdx.x >> 6;
    const int b    = blockIdx.y;
    const int px0  = blockIdx.x * 128 + wv * 32;

    const int pxa = px0 + (lane & 15);
    const int chl = (lane >> 4) << 3;
    const unsigned short* __restrict__ apx = A + ((size_t)b * C_ + chl) * HW + pxa;
    const unsigned short* __restrict__ rp = rfrag + (size_t)b * 8192 + lane * 8;

    f32x4 acc[2][4];
#pragma unroll
    for (int xt = 0; xt < 2; ++xt)
#pragma unroll
        for (int t = 0; t < 4; ++t) acc[xt][t] = (f32x4)0.f;

#pragma unroll 1
    for (int ks = 0; ks < 2; ++ks) {
        bf16x8 xa, xb;
#pragma unroll
        for (int j = 0; j < 8; ++j) {
            const unsigned short* p0 = apx + (size_t)(ks * 32 + j) * HW;
            xa[j] = (short)p0[0];
            xb[j] = (short)p0[16];
        }
        const unsigned short* __restrict__ rk = rp + (size_t)ks * 8 * 512;
        bf16x8 rh = *reinterpret_cast<const bf16x8*>(rk);
        bf16x8 rl = *reinterpret_cast<const bf16x8*>(rk + 4 * 512);
#pragma unroll
        for (int t = 0; t < 4; ++t) {
            bf16x8 rhn, rln;
            if (t < 3) {
                rhn = *reinterpret_cast<const bf16x8*>(rk + (t + 1) * 512);
                rln = *reinterpret_cast<const bf16x8*>(rk + (4 + t + 1) * 512);
            }
            acc[0][t] = __builtin_amdgcn_mfma_f32_16x16x32_bf16(rh, xa, acc[0][t], 0, 0, 0);
            acc[0][t] = __builtin_amdgcn_mfma_f32_16x16x32_bf16(rl, xa, acc[0][t], 0, 0, 0);
            acc[1][t] = __builtin_amdgcn_mfma_f32_16x16x32_bf16(rh, xb, acc[1][t], 0, 0, 0);
            acc[1][t] = __builtin_amdgcn_mfma_f32_16x16x32_bf16(rl, xb, acc[1][t], 0, 0, 0);
            rh = rhn; rl = rln;
        }
    }

    // epilogue: t = (feat_e + A) * fu, write bf16
    const int orow = (lane >> 4) << 2;
    const unsigned short* __restrict__ ares = A + (size_t)b * C_ * HW + px0 + (lane & 15);
    unsigned short* __restrict__ op        = tout + (size_t)b * C_ * HW + px0 + (lane & 15);
#pragma unroll
    for (int xt = 0; xt < 2; ++xt)
#pragma unroll
        for (int t = 0; t < 4; ++t)
#pragma unroll
            for (int reg = 0; reg < 4; ++reg) {
                const int oc = t * 16 + orow + reg;
                float r = acc[xt][t][reg] + bf2f(ares[(size_t)oc * HW + xt * 16]);
                op[(size_t)oc * HW + xt * 16] = f2bf(r * fu[oc]);
            }
}

// ---------------- K8: row softmax (bf16 input) + dsnt; fp32 heatmap out -------
__global__ __launch_bounds__(512) void k_softmax_dsnt(const unsigned short* __restrict__ in0,
                                                      float* __restrict__ pout,
                                                      float* __restrict__ coords) {
    const int row = blockIdx.x;                  // b*64 + c
    const int tid = threadIdx.x;
    const u16x8* in08 = reinterpret_cast<const u16x8*>(in0 + (size_t)row * HW);
    float4*      out4 = reinterpret_cast<float4*>(pout + (size_t)row * HW);
    __shared__ float rowbuf[HW];                 // 40 KB
    __shared__ float red[32];
    float4* r4 = reinterpret_cast<float4*>(rowbuf);

    float m = -3.402823466e38f;
    for (int j = tid; j < HW/8; j += 512) {
        u16x8 u = in08[j];
        float4 a, bv;
        a.x  = bf2f(u[0]); a.y  = bf2f(u[1]); a.z  = bf2f(u[2]); a.w  = bf2f(u[3]);
        bv.x = bf2f(u[4]); bv.y = bf2f(u[5]); bv.z = bf2f(u[6]); bv.w = bf2f(u[7]);
        r4[2*j]     = a;
        r4[2*j + 1] = bv;
        m = fmaxf(m, fmaxf(fmaxf(a.x, a.y), fmaxf(a.z, a.w)));
        m = fmaxf(m, fmaxf(fmaxf(bv.x, bv.y), fmaxf(bv.z, bv.w)));
    }
#pragma unroll
    for (int off = 32; off > 0; off >>= 1) m = fmaxf(m, __shfl_xor(m, off));
    if ((tid & 63) == 0) red[tid >> 6] = m;
    __syncthreads();
#pragma unroll
    for (int q = 0; q < 8; ++q) m = fmaxf(m, red[q]);

    const float invw = 1.f / W_, invh = 1.f / H_;
    float s = 0.f, sx = 0.f, sy = 0.f;
    for (int j = tid; j < HW/4; j += 512) {
        float4 u = r4[j];
        int e0 = j * 4;
        int h  = e0 / W_;
        int w0 = e0 - h * W_;
        float y  = (2*h + 1) * invh - 1.f;
        float x0 = (2*w0 + 1) * invw - 1.f;
        float4 e;
        e.x = __expf(u.x - m); s += e.x; sy = fmaf(e.x, y, sy); sx = fmaf(e.x, x0,          sx);
        e.y = __expf(u.y - m); s += e.y; sy = fmaf(e.y, y, sy); sx = fmaf(e.y, x0 + 2*invw, sx);
        e.z = __expf(u.z - m); s += e.z; sy = fmaf(e.z, y, sy); sx = fmaf(e.z, x0 + 4*invw, sx);
        e.w = __expf(u.w - m); s += e.w; sy = fmaf(e.w, y, sy); sx = fmaf(e.w, x0 + 6*invw, sx);
        r4[j] = e;                               // store unnormalized exp
    }
#pragma unroll
    for (int off = 32; off > 0; off >>= 1) {
        s  += __shfl_xor(s,  off);
        sx += __shfl_xor(sx, off);
        sy += __shfl_xor(sy, off);
    }
    if ((tid & 63) == 0) { int w = tid >> 6; red[8+w] = s; red[16+w] = sx; red[24+w] = sy; }
    __syncthreads();
    s = 0.f; sx = 0.f; sy = 0.f;
#pragma unroll
    for (int q = 0; q < 8; ++q) { s += red[8+q]; sx += red[16+q]; sy += red[24+q]; }
    float inv = 1.f / s;

    for (int j = tid; j < HW/4; j += 512) {
        float4 e = r4[j];
        e.x *= inv; e.y *= inv; e.z *= inv; e.w *= inv;
        out4[j] = e;
    }
    if (tid == 0) {
        coords[row*2 + 0] = sx * inv;
        coords[row*2 + 1] = sy * inv;
    }
}

// ------------------------------------------------------------------------------
extern "C" void kernel_launch(void* const* d_in, const int* in_sizes, int n_in,
                              void* d_out, int out_size, void* d_ws, size_t ws_size,
                              hipStream_t stream) {
    const float* fcn = (const float*)d_in[0];
    const float* hmw = (const float*)d_in[1];
    const float* dww = (const float*)d_in[2];
    const float* fuw = (const float*)d_in[3];
    float* out = (float*)d_out;
    char* ws = (char*)d_ws;

    size_t off = 0;
    unsigned short* wfrag = (unsigned short*)(ws + off); off += 131072;          // 128 KB
    float*          buf1  = (float*)         (ws + off); off += 41943040;        // 42 MB (unnorm)
    unsigned short* abf   = (unsigned short*)(ws + off); off += 20971520;        // 21 MB (A bf16)
    float*          part  = (float*)         (ws + off); off += (size_t)NCH*16*4096*4; // 4 MB
    unsigned short* rfrag = (unsigned short*)(ws + off); off += 262144;          // 256 KB
    unsigned short* tbuf  = (unsigned short*)(ws + off); off += 20971520;        // 21 MB (t bf16)

    float* hm2            = out + 4096;   // final heatmaps (fp32)
    float* final_coords   = out;
    float* interme_coords = out + 2048;

    hipLaunchKernelGGL(k_prep_w,            dim3(256),      dim3(256), 0, stream, hmw, wfrag);
    hipLaunchKernelGGL(k_gemm1_mfma,        dim3(40, 16),   dim3(512), 0, stream, fcn, wfrag, buf1);
    hipLaunchKernelGGL(k_softmax_dsnt_conv, dim3(1024),     dim3(512), 0, stream, buf1, dww, abf, interme_coords);
    hipLaunchKernelGGL(k_rel_partial,       dim3(NCH, 16),  dim3(256), 0, stream, abf, part);
    hipLaunchKernelGGL(k_rel_finalize,      dim3(16),       dim3(256), 0, stream, part, rfrag);
    hipLaunchKernelGGL(k_feate_mfma,        dim3(80, 16),   dim3(256), 0, stream, abf, rfrag, fuw, tbuf);
    hipLaunchKernelGGL(k_softmax_dsnt,      dim3(1024),     dim3(512), 0, stream, tbuf, hm2, final_coords);
}

// Round 19
// 159.846 us; speedup vs baseline: 2.1948x; 1.0418x over previous
//
#include <hip/hip_runtime.h>

#define B_  16
#define CIN 512
#define C_  64
#define H_  64
#define W_  160
#define HW  (H_*W_)   // 10240
#define NCH 16        // relation hw-chunks per batch (640 hw each)

typedef __attribute__((ext_vector_type(8))) short bf16x8;
typedef __attribute__((ext_vector_type(4))) float f32x4;
typedef __attribute__((ext_vector_type(8))) unsigned short u16x8;
typedef __attribute__((ext_vector_type(4))) unsigned short u16x4;

// RNE float -> bf16
__device__ inline unsigned short f2bf(float x) {
    unsigned u = __float_as_uint(x);
    return (unsigned short)((u + 0x7FFF + ((u >> 16) & 1)) >> 16);
}
__device__ inline float bf2f(unsigned short v) {
    return __uint_as_float((unsigned)v << 16);
}

// RNE float -> bf16 hi, then RNE bf16 of the remainder (weight prep)
__device__ inline void bf16_split(float x, unsigned short& h, unsigned short& l) {
    h = f2bf(x);
    float lo = x - bf2f(h);
    l = f2bf(lo);
}

// Truncation split (gemm1 hot path)
__device__ inline void bf16_tsplit(float x, short& h, short& l) {
    unsigned u = __float_as_uint(x);
    h = (short)(u >> 16);
    float hf = __uint_as_float(u & 0xFFFF0000u);
    float lo = x - hf;
    l = (short)(__float_as_uint(lo) >> 16);
}

// ---------------- K1: pack hm_w into MFMA-fragment-ordered hi/lo bf16 ---------
__global__ __launch_bounds__(256) void k_prep_w(const float* __restrict__ hmw,
                                                unsigned short* __restrict__ wfrag) {
    int tid  = blockIdx.x * 256 + threadIdx.x;        // 0 .. 65535
    int j    = tid & 7;
    int lane = (tid >> 3) & 63;
    int t    = (tid >> 9) & 3;
    int p    = (tid >> 11) & 1;
    int ks   = tid >> 12;
    int o = t * 16 + (lane & 15);
    int k = ks * 32 + ((lane >> 4) << 3) + j;
    float val = hmw[o * CIN + k];
    unsigned short h, l;
    bf16_split(val, h, l);
    wfrag[tid] = p ? l : h;
}

// ---------------- K2: unnorm = fcn x W via bf16 hi/lo MFMA --------------------
// Counted-vmcnt pipeline (verified R16: ~79 us).
__global__ __launch_bounds__(512, 4) void k_gemm1_mfma(const float* __restrict__ fcn,
                                                       const unsigned short* __restrict__ wfrag,
                                                       float* __restrict__ out) {
    const int lane  = threadIdx.x & 63;
    const int wv    = threadIdx.x >> 6;               // 0..7
    const int b     = blockIdx.y;
    const int pxblk = blockIdx.x * 256;               // block's 256-px window

    __shared__ float xs[2][32 * 256];                 // 2 x 32 KB x-tiles
    __shared__ unsigned short wsh[2][4096];           // 2 x 8 KB w-tiles

    const int chl  = (lane >> 4) << 3;
    const int pxw  = wv * 32;
    const int px16 = lane & 15;

    const size_t gbase = (size_t)b * CIN * HW + pxblk + (lane << 2);
    const int    grow0 = wv << 2;
    const int    lbase = grow0 * 256;

#define STAGE(buf, ks)                                                                  \
    {                                                                                   \
        _Pragma("unroll")                                                               \
        for (int i = 0; i < 4; ++i) {                                                   \
            const float* g = fcn + gbase + (size_t)((ks) * 32 + grow0 + i) * HW;        \
            float* l = &xs[(buf)][lbase + i * 256];                                     \
            __builtin_amdgcn_global_load_lds(                                           \
                (const __attribute__((address_space(1))) void*)g,                       \
                (__attribute__((address_space(3))) void*)l, 16, 0, 0);                  \
        }                                                                               \
        {                                                                               \
            const unsigned short* g = wfrag + (ks) * 4096 + wv * 512 + lane * 8;        \
            unsigned short* l = &wsh[(buf)][wv * 512];                                  \
            __builtin_amdgcn_global_load_lds(                                           \
                (const __attribute__((address_space(1))) void*)g,                       \
                (__attribute__((address_space(3))) void*)l, 16, 0, 0);                  \
        }                                                                               \
    }

    f32x4 acc[2][4];
#pragma unroll
    for (int xt = 0; xt < 2; ++xt)
#pragma unroll
        for (int t = 0; t < 4; ++t) acc[xt][t] = (f32x4)0.f;

#define COMPUTE(bb)                                                                     \
    {                                                                                   \
        float xa[8], xb[8];                                                             \
        _Pragma("unroll")                                                               \
        for (int j = 0; j < 8; ++j) {                                                   \
            const float* r = &xs[(bb)][(chl + j) * 256 + pxw + px16];                   \
            xa[j] = r[0];                                                               \
            xb[j] = r[16];                                                              \
        }                                                                               \
        bf16x8 xah, xal, xbh, xbl;                                                      \
        _Pragma("unroll")                                                               \
        for (int j = 0; j < 8; ++j) {                                                   \
            short h, l;                                                                 \
            bf16_tsplit(xa[j], h, l);                                                   \
            xah[j] = h; xal[j] = l;                                                     \
            bf16_tsplit(xb[j], h, l);                                                   \
            xbh[j] = h; xbl[j] = l;                                                     \
        }                                                                               \
        const unsigned short* wk = &wsh[(bb)][0];                                       \
        bf16x8 wh = *reinterpret_cast<const bf16x8*>(wk + (lane << 3));                 \
        bf16x8 wl = *reinterpret_cast<const bf16x8*>(wk + ((4 * 64 + lane) << 3));      \
        _Pragma("unroll")                                                               \
        for (int t = 0; t < 4; ++t) {                                                   \
            bf16x8 whn, wln;                                                            \
            if (t < 3) {                                                                \
                whn = *reinterpret_cast<const bf16x8*>(wk + (((t + 1) * 64 + lane) << 3)); \
                wln = *reinterpret_cast<const bf16x8*>(wk + (((5 + t) * 64 + lane) << 3)); \
            }                                                                           \
            acc[0][t] = __builtin_amdgcn_mfma_f32_16x16x32_bf16(wh, xah, acc[0][t], 0, 0, 0); \
            acc[0][t] = __builtin_amdgcn_mfma_f32_16x16x32_bf16(wh, xal, acc[0][t], 0, 0, 0); \
            acc[0][t] = __builtin_amdgcn_mfma_f32_16x16x32_bf16(wl, xah, acc[0][t], 0, 0, 0); \
            acc[1][t] = __builtin_amdgcn_mfma_f32_16x16x32_bf16(wh, xbh, acc[1][t], 0, 0, 0); \
            acc[1][t] = __builtin_amdgcn_mfma_f32_16x16x32_bf16(wh, xbl, acc[1][t], 0, 0, 0); \
            acc[1][t] = __builtin_amdgcn_mfma_f32_16x16x32_bf16(wl, xbh, acc[1][t], 0, 0, 0); \
            wh = whn; wl = wln;                                                         \
        }                                                                               \
    }

    STAGE(0, 0);
    asm volatile("s_waitcnt vmcnt(0)" ::: "memory");
    __builtin_amdgcn_sched_barrier(0);
    __builtin_amdgcn_s_barrier();

    int cur = 0;
#pragma unroll 1
    for (int ks = 0; ks < 15; ++ks) {
        STAGE(cur ^ 1, ks + 1);                       // issue next tile (stays in flight)
        asm volatile("s_waitcnt vmcnt(5)" ::: "memory");  // own step-ks loads complete
        __builtin_amdgcn_sched_barrier(0);
        __builtin_amdgcn_s_barrier();                 // all waves' step-ks loads landed
        COMPUTE(cur);
        __builtin_amdgcn_s_barrier();                 // done reading cur (overwritten next iter)
        cur ^= 1;
    }
    asm volatile("s_waitcnt vmcnt(0)" ::: "memory");
    __builtin_amdgcn_sched_barrier(0);
    __builtin_amdgcn_s_barrier();
    COMPUTE(cur);
#undef STAGE
#undef COMPUTE

    const int orow = (lane >> 4) << 2;
    float* __restrict__ op = out + (size_t)b * C_ * HW + pxblk + pxw + px16;
#pragma unroll
    for (int xt = 0; xt < 2; ++xt)
#pragma unroll
        for (int t = 0; t < 4; ++t)
#pragma unroll
            for (int reg = 0; reg < 4; ++reg)
                op[(size_t)(t * 16 + orow + reg) * HW + xt * 16] = acc[xt][t][reg];
}

// ------- K3: softmax + dsnt + FUSED depthwise conv; A written as bf16 ---------
// 512 threads / row. Reg-carry: each thread holds its 5 float4 chunks in
// registers; raw-value LDS write/read passes eliminated (only exp written to
// LDS for the conv neighborhood phase). Conv: sliding-window (R18).
__global__ __launch_bounds__(512) void k_softmax_dsnt_conv(const float* __restrict__ in0,
                                                           const float* __restrict__ dw,
                                                           unsigned short* __restrict__ aout,
                                                           float* __restrict__ coords) {
    const int row = blockIdx.x;                  // b*64 + c
    const int c   = row & (C_ - 1);
    const int tid = threadIdx.x;
    const float4* in04 = reinterpret_cast<const float4*>(in0 + (size_t)row * HW);
    __shared__ float rowbuf[HW];                 // 40 KB (exp values)
    __shared__ float red[32];
    float4* r4 = reinterpret_cast<float4*>(rowbuf);

    float4 vals[5];
    float m = -3.402823466e38f;
#pragma unroll
    for (int k = 0; k < 5; ++k) {
        float4 u = in04[tid + k * 512];
        vals[k] = u;
        m = fmaxf(m, fmaxf(fmaxf(u.x, u.y), fmaxf(u.z, u.w)));
    }
#pragma unroll
    for (int off = 32; off > 0; off >>= 1) m = fmaxf(m, __shfl_xor(m, off));
    if ((tid & 63) == 0) red[tid >> 6] = m;
    __syncthreads();
#pragma unroll
    for (int q = 0; q < 8; ++q) m = fmaxf(m, red[q]);

    const float invw = 1.f / W_, invh = 1.f / H_;
    float s = 0.f, sx = 0.f, sy = 0.f;
#pragma unroll
    for (int k = 0; k < 5; ++k) {
        const int j = tid + k * 512;
        float4 u = vals[k];
        int e0 = j * 4;
        int h  = e0 / W_;
        int w0 = e0 - h * W_;
        float y  = (2*h + 1) * invh - 1.f;
        float x0 = (2*w0 + 1) * invw - 1.f;
        float4 e;
        e.x = __expf(u.x - m); s += e.x; sy = fmaf(e.x, y, sy); sx = fmaf(e.x, x0,          sx);
        e.y = __expf(u.y - m); s += e.y; sy = fmaf(e.y, y, sy); sx = fmaf(e.y, x0 + 2*invw, sx);
        e.z = __expf(u.z - m); s += e.z; sy = fmaf(e.z, y, sy); sx = fmaf(e.z, x0 + 4*invw, sx);
        e.w = __expf(u.w - m); s += e.w; sy = fmaf(e.w, y, sy); sx = fmaf(e.w, x0 + 6*invw, sx);
        r4[j] = e;                               // store unnormalized exp (for conv)
    }
#pragma unroll
    for (int off = 32; off > 0; off >>= 1) {
        s  += __shfl_xor(s,  off);
        sx += __shfl_xor(sx, off);
        sy += __shfl_xor(sy, off);
    }
    if ((tid & 63) == 0) { int w = tid >> 6; red[8+w] = s; red[16+w] = sx; red[24+w] = sy; }
    __syncthreads();                             // also fences all r4 writes
    s = 0.f; sx = 0.f; sy = 0.f;
#pragma unroll
    for (int q = 0; q < 8; ++q) { s += red[8+q]; sx += red[16+q]; sy += red[24+q]; }
    float inv = 1.f / s;

    if (tid == 0) {
        coords[row*2 + 0] = sx * inv;
        coords[row*2 + 1] = sy * inv;
    }

    float wv[25];
#pragma unroll
    for (int k = 0; k < 25; ++k) wv[k] = dw[c * 25 + k];

    // ---- conv phase: thread -> (image row ir, 20-px segment sg) ----
    const int ir = tid >> 3;                     // 0..63
    const int sg = tid & 7;                      // 0..7
    float a20[20];
#pragma unroll
    for (int p = 0; p < 20; ++p) a20[p] = 0.f;
#pragma unroll
    for (int dy = 0; dy < 5; ++dy) {
        int rr = ir + dy - 2;
        if (rr < 0 || rr >= H_) continue;
        const float4* rp = reinterpret_cast<const float4*>(rowbuf + rr * W_);
        float w28[28];
#pragma unroll
        for (int q = 0; q < 7; ++q) {
            int f4i = sg * 5 - 1 + q;
            if (f4i >= 0 && f4i < 40) {
                float4 v = rp[f4i];
                w28[q*4+0] = v.x; w28[q*4+1] = v.y; w28[q*4+2] = v.z; w28[q*4+3] = v.w;
            } else {
                w28[q*4+0] = 0.f; w28[q*4+1] = 0.f; w28[q*4+2] = 0.f; w28[q*4+3] = 0.f;
            }
        }
        const float* wr = wv + dy * 5;
#pragma unroll
        for (int dx = 0; dx < 5; ++dx) {
            float wt = wr[dx];
#pragma unroll
            for (int p = 0; p < 20; ++p)
                a20[p] = fmaf(w28[p + 2 + dx], wt, a20[p]);
        }
    }
    unsigned short* ao = aout + (size_t)row * HW + ir * W_ + sg * 20;
#pragma unroll
    for (int k4 = 0; k4 < 5; ++k4) {
        u16x4 ov;
        ov[0] = f2bf(a20[k4*4+0] * inv);
        ov[1] = f2bf(a20[k4*4+1] * inv);
        ov[2] = f2bf(a20[k4*4+2] * inv);
        ov[3] = f2bf(a20[k4*4+3] * inv);
        *reinterpret_cast<u16x4*>(ao + k4 * 4) = ov;
    }
}

// ------- K5: relation partials A·A^T via MFMA (no LDS, no barriers) -----------
__global__ __launch_bounds__(256) void k_rel_partial(const unsigned short* __restrict__ A,
                                                     float* __restrict__ part) {
    const int b  = blockIdx.y, ch = blockIdx.x;
    const int lane = threadIdx.x & 63;
    const int w    = threadIdx.x >> 6;          // wave's cg (0..3)
    const int hwb  = ch * (HW / NCH);           // 640-hw chunk
    const unsigned short* __restrict__ ab = A + (size_t)b * C_ * HW;
    const int r16 = lane & 15, h8 = (lane >> 4) << 3;
    const unsigned short* __restrict__ own = ab + (size_t)(w * 16 + r16) * HW;

    f32x4 acc[4];
#pragma unroll
    for (int d = 0; d < 4; ++d) acc[d] = (f32x4)0.f;

#pragma unroll 1
    for (int kk = 0; kk < (HW / NCH) / 32; ++kk) {
        const int hw0 = hwb + kk * 32 + h8;
        bf16x8 fra = *reinterpret_cast<const bf16x8*>(own + hw0);
#pragma unroll
        for (int d = 0; d < 4; ++d) {
            bf16x8 frb = *reinterpret_cast<const bf16x8*>(ab + (size_t)(d * 16 + r16) * HW + hw0);
            acc[d] = __builtin_amdgcn_mfma_f32_16x16x32_bf16(fra, frb, acc[d], 0, 0, 0);
        }
    }

    float* __restrict__ pp = part + (size_t)(b * NCH + ch) * 4096;
    const int crow = w * 16 + ((lane >> 4) << 2);
#pragma unroll
    for (int d = 0; d < 4; ++d)
#pragma unroll
        for (int reg = 0; reg < 4; ++reg)
            pp[(crow + reg) * 64 + d * 16 + r16] = acc[d][reg];
}

// ------ K6: reduce partials, rowmax-sub softmax, pack R as MFMA frags ---------
__global__ __launch_bounds__(256) void k_rel_finalize(const float* __restrict__ part,
                                                      unsigned short* __restrict__ rfrag) {
    const int b = blockIdx.x;
    __shared__ float rel[64][65];
    __shared__ float Rs[64][64];
    for (int e = threadIdx.x; e < 4096; e += 256) {
        float s = 0.f;
        for (int k = 0; k < NCH; ++k) s += part[(size_t)(b * NCH + k) * 4096 + e];
        rel[e >> 6][e & 63] = s;
    }
    __syncthreads();
    if (threadIdx.x < 64) {
        int cc = threadIdx.x;
        // softmax(rowmax - r) == exp(rowmin - r) / sum(exp(rowmin - r))
        float mn = rel[cc][0];
        for (int d = 1; d < 64; ++d) mn = fminf(mn, rel[cc][d]);
        float s = 0.f;
        for (int d = 0; d < 64; ++d) s += __expf(mn - rel[cc][d]);
        float inv = 1.f / s;
        for (int d = 0; d < 64; ++d)
            Rs[cc][d] = __expf(mn - rel[cc][d]) * inv;
    }
    __syncthreads();
    unsigned short* __restrict__ rb = rfrag + (size_t)b * 8192;
    for (int idx = threadIdx.x; idx < 1024; idx += 256) {
        int lane = idx & 63;
        int rest = idx >> 6;          // ks*8 + p*4 + t
        int t  = rest & 3;
        int p  = (rest >> 2) & 1;
        int ks = rest >> 3;
        int o  = t * 16 + (lane & 15);
        int d0 = ks * 32 + ((lane >> 4) << 3);
        bf16x8 v;
#pragma unroll
        for (int j = 0; j < 8; ++j) {
            unsigned short h, l;
            bf16_split(Rs[o][d0 + j], h, l);
            v[j] = (short)(p ? l : h);
        }
        *reinterpret_cast<bf16x8*>(rb + idx * 8) = v;
    }
}

// ------- K7: feat_e = R·A (A single bf16, R hi/lo); t=(fe+A)*fu -> bf16 -------
__global__ __launch_bounds__(256, 5) void k_feate_mfma(const unsigned short* __restrict__ A,
                                                       const unsigned short* __restrict__ rfrag,
                                                       const float* __restrict__ fu,
                                                       unsigned short* __restrict__ tout) {
    const int lane = threadIdx.x & 63;
    const int wv   = threadIdx.x >> 6;
    const int b    = blockIdx.y;
    const int px0  = blockIdx.x * 128 + wv * 32;

    const int pxa = px0 + (lane & 15);
    const int chl = (lane >> 4) << 3;
    const unsigned short* __restrict__ apx = A + ((size_t)b * C_ + chl) * HW + pxa;
    const unsigned short* __restrict__ rp = rfrag + (size_t)b * 8192 + lane * 8;

    f32x4 acc[2][4];
#pragma unroll
    for (int xt = 0; xt < 2; ++xt)
#pragma unroll
        for (int t = 0; t < 4; ++t) acc[xt][t] = (f32x4)0.f;

#pragma unroll 1
    for (int ks = 0; ks < 2; ++ks) {
        bf16x8 xa, xb;
#pragma unroll
        for (int j = 0; j < 8; ++j) {
            const unsigned short* p0 = apx + (size_t)(ks * 32 + j) * HW;
            xa[j] = (short)p0[0];
            xb[j] = (short)p0[16];
        }
        const unsigned short* __restrict__ rk = rp + (size_t)ks * 8 * 512;
        bf16x8 rh = *reinterpret_cast<const bf16x8*>(rk);
        bf16x8 rl = *reinterpret_cast<const bf16x8*>(rk + 4 * 512);
#pragma unroll
        for (int t = 0; t < 4; ++t) {
            bf16x8 rhn, rln;
            if (t < 3) {
                rhn = *reinterpret_cast<const bf16x8*>(rk + (t + 1) * 512);
                rln = *reinterpret_cast<const bf16x8*>(rk + (4 + t + 1) * 512);
            }
            acc[0][t] = __builtin_amdgcn_mfma_f32_16x16x32_bf16(rh, xa, acc[0][t], 0, 0, 0);
            acc[0][t] = __builtin_amdgcn_mfma_f32_16x16x32_bf16(rl, xa, acc[0][t], 0, 0, 0);
            acc[1][t] = __builtin_amdgcn_mfma_f32_16x16x32_bf16(rh, xb, acc[1][t], 0, 0, 0);
            acc[1][t] = __builtin_amdgcn_mfma_f32_16x16x32_bf16(rl, xb, acc[1][t], 0, 0, 0);
            rh = rhn; rl = rln;
        }
    }

    // epilogue: t = (feat_e + A) * fu, write bf16
    const int orow = (lane >> 4) << 2;
    const unsigned short* __restrict__ ares = A + (size_t)b * C_ * HW + px0 + (lane & 15);
    unsigned short* __restrict__ op        = tout + (size_t)b * C_ * HW + px0 + (lane & 15);
#pragma unroll
    for (int xt = 0; xt < 2; ++xt)
#pragma unroll
        for (int t = 0; t < 4; ++t)
#pragma unroll
            for (int reg = 0; reg < 4; ++reg) {
                const int oc = t * 16 + orow + reg;
                float r = acc[xt][t][reg] + bf2f(ares[(size_t)oc * HW + xt * 16]);
                op[(size_t)oc * HW + xt * 16] = f2bf(r * fu[oc]);
            }
}

// ---------------- K8: row softmax (bf16 input) + dsnt; fp32 heatmap out -------
// Reg-carry: NO LDS row buffer — values live in 5 float4 regs; exp overwrites
// them; final pass writes e*inv straight to global.
__global__ __launch_bounds__(512) void k_softmax_dsnt(const unsigned short* __restrict__ in0,
                                                      float* __restrict__ pout,
                                                      float* __restrict__ coords) {
    const int row = blockIdx.x;                  // b*64 + c
    const int tid = threadIdx.x;
    const u16x4* in04 = reinterpret_cast<const u16x4*>(in0 + (size_t)row * HW);
    float4*      out4 = reinterpret_cast<float4*>(pout + (size_t)row * HW);
    __shared__ float red[32];

    float4 vals[5];
    float m = -3.402823466e38f;
#pragma unroll
    for (int k = 0; k < 5; ++k) {
        u16x4 v = in04[tid + k * 512];
        float4 u;
        u.x = bf2f(v[0]); u.y = bf2f(v[1]); u.z = bf2f(v[2]); u.w = bf2f(v[3]);
        vals[k] = u;
        m = fmaxf(m, fmaxf(fmaxf(u.x, u.y), fmaxf(u.z, u.w)));
    }
#pragma unroll
    for (int off = 32; off > 0; off >>= 1) m = fmaxf(m, __shfl_xor(m, off));
    if ((tid & 63) == 0) red[tid >> 6] = m;
    __syncthreads();
#pragma unroll
    for (int q = 0; q < 8; ++q) m = fmaxf(m, red[q]);

    const float invw = 1.f / W_, invh = 1.f / H_;
    float s = 0.f, sx = 0.f, sy = 0.f;
#pragma unroll
    for (int k = 0; k < 5; ++k) {
        const int j = tid + k * 512;
        float4 u = vals[k];
        int e0 = j * 4;
        int h  = e0 / W_;
        int w0 = e0 - h * W_;
        float y  = (2*h + 1) * invh - 1.f;
        float x0 = (2*w0 + 1) * invw - 1.f;
        float4 e;
        e.x = __expf(u.x - m); s += e.x; sy = fmaf(e.x, y, sy); sx = fmaf(e.x, x0,          sx);
        e.y = __expf(u.y - m); s += e.y; sy = fmaf(e.y, y, sy); sx = fmaf(e.y, x0 + 2*invw, sx);
        e.z = __expf(u.z - m); s += e.z; sy = fmaf(e.z, y, sy); sx = fmaf(e.z, x0 + 4*invw, sx);
        e.w = __expf(u.w - m); s += e.w; sy = fmaf(e.w, y, sy); sx = fmaf(e.w, x0 + 6*invw, sx);
        vals[k] = e;                             // keep unnormalized exp in regs
    }
#pragma unroll
    for (int off = 32; off > 0; off >>= 1) {
        s  += __shfl_xor(s,  off);
        sx += __shfl_xor(sx, off);
        sy += __shfl_xor(sy, off);
    }
    if ((tid & 63) == 0) { int w = tid >> 6; red[8+w] = s; red[16+w] = sx; red[24+w] = sy; }
    __syncthreads();
    s = 0.f; sx = 0.f; sy = 0.f;
#pragma unroll
    for (int q = 0; q < 8; ++q) { s += red[8+q]; sx += red[16+q]; sy += red[24+q]; }
    float inv = 1.f / s;

#pragma unroll
    for (int k = 0; k < 5; ++k) {
        float4 e = vals[k];
        e.x *= inv; e.y *= inv; e.z *= inv; e.w *= inv;
        out4[tid + k * 512] = e;
    }
    if (tid == 0) {
        coords[row*2 + 0] = sx * inv;
        coords[row*2 + 1] = sy * inv;
    }
}

// ------------------------------------------------------------------------------
extern "C" void kernel_launch(void* const* d_in, const int* in_sizes, int n_in,
                              void* d_out, int out_size, void* d_ws, size_t ws_size,
                              hipStream_t stream) {
    const float* fcn = (const float*)d_in[0];
    const float* hmw = (const float*)d_in[1];
    const float* dww = (const float*)d_in[2];
    const float* fuw = (const float*)d_in[3];
    float* out = (float*)d_out;
    char* ws = (char*)d_ws;

    size_t off = 0;
    unsigned short* wfrag = (unsigned short*)(ws + off); off += 131072;          // 128 KB
    float*          buf1  = (float*)         (ws + off); off += 41943040;        // 42 MB (unnorm)
    unsigned short* abf   = (unsigned short*)(ws + off); off += 20971520;        // 21 MB (A bf16)
    float*          part  = (float*)         (ws + off); off += (size_t)NCH*16*4096*4; // 4 MB
    unsigned short* rfrag = (unsigned short*)(ws + off); off += 262144;          // 256 KB
    unsigned short* tbuf  = (unsigned short*)(ws + off); off += 20971520;        // 21 MB (t bf16)

    float* hm2            = out + 4096;   // final heatmaps (fp32)
    float* final_coords   = out;
    float* interme_coords = out + 2048;

    hipLaunchKernelGGL(k_prep_w,            dim3(256),      dim3(256), 0, stream, hmw, wfrag);
    hipLaunchKernelGGL(k_gemm1_mfma,        dim3(40, 16),   dim3(512), 0, stream, fcn, wfrag, buf1);
    hipLaunchKernelGGL(k_softmax_dsnt_conv, dim3(1024),     dim3(512), 0, stream, buf1, dww, abf, interme_coords);
    hipLaunchKernelGGL(k_rel_partial,       dim3(NCH, 16),  dim3(256), 0, stream, abf, part);
    hipLaunchKernelGGL(k_rel_finalize,      dim3(16),       dim3(256), 0, stream, part, rfrag);
    hipLaunchKernelGGL(k_feate_mfma,        dim3(80, 16),   dim3(256), 0, stream, abf, rfrag, fuw, tbuf);
    hipLaunchKernelGGL(k_softmax_dsnt,      dim3(1024),     dim3(512), 0, stream, tbuf, hm2, final_coords);
}